// Round 8
// baseline (2199.538 us; speedup 1.0000x reference)
//
#include <hip/hip_runtime.h>
#include <hip/hip_bf16.h>
#include <math.h>

constexpr int Dd  = 768;
constexpr int NH  = 12;
constexpr int DHd = 64;
constexpr int Bn  = 8;
constexpr int TVn = 512;
constexpr int TSn = 128;
constexpr int NST = 8;
constexpr int An  = 16;
constexpr int DPn = 3072;
constexpr int GSn = 2304;
constexpr int Mtot = 14464;   // 128 (s=0) + 8*7*16*16 candidate rows; 226*64

typedef unsigned short us;
using short8   = __attribute__((ext_vector_type(8))) short;
using floatx16 = __attribute__((ext_vector_type(16))) float;

__device__ inline us f2bf(float x) {
  union { float f; unsigned u; } a; a.f = x;
  return (us)((a.u + 0x7fffu + ((a.u >> 16) & 1u)) >> 16);
}
__device__ inline float bf2f(us h) {
  union { unsigned u; float f; } a; a.u = ((unsigned)h) << 16;
  return a.f;
}

// ---------------------------------------------------------------------------
// splits (float4-vectorized; n4 = n/4)
// ---------------------------------------------------------------------------
__global__ void split_k(const float* __restrict__ x, us* __restrict__ h,
                        us* __restrict__ l, int n4) {
  for (int i = blockIdx.x * 256 + threadIdx.x; i < n4; i += gridDim.x * 256) {
    float4 v = ((const float4*)x)[i];
    float vv[4] = {v.x, v.y, v.z, v.w};
    union { us u[4]; uint2 w; } hh, ll;
#pragma unroll
    for (int t = 0; t < 4; t++) {
      us hb = f2bf(vv[t]);
      hh.u[t] = hb;
      ll.u[t] = f2bf(vv[t] - bf2f(hb));
    }
    ((uint2*)h)[i] = hh.w;
    ((uint2*)l)[i] = ll.w;
  }
}

__global__ void split4_k(const float* s0, us* h0, us* l0, int n0,
                         const float* s1, us* h1, us* l1, int n1,
                         const float* s2, us* h2, us* l2, int n2,
                         const float* s3, us* h3, us* l3, int n3) {
  const float* s; us* h; us* l; int n;
  switch (blockIdx.y) {
    case 0: s = s0; h = h0; l = l0; n = n0; break;
    case 1: s = s1; h = h1; l = l1; n = n1; break;
    case 2: s = s2; h = h2; l = l2; n = n2; break;
    default: s = s3; h = h3; l = l3; n = n3; break;
  }
  int n4 = n >> 2;
  for (int i = blockIdx.x * 256 + threadIdx.x; i < n4; i += gridDim.x * 256) {
    float4 v = ((const float4*)s)[i];
    float vv[4] = {v.x, v.y, v.z, v.w};
    union { us u[4]; uint2 w; } hh, ll;
#pragma unroll
    for (int t = 0; t < 4; t++) {
      us hb = f2bf(vv[t]);
      hh.u[t] = hb;
      ll.u[t] = f2bf(vv[t] - bf2f(hb));
    }
    ((uint2*)h)[i] = hh.w;
    ((uint2*)l)[i] = ll.w;
  }
}

__device__ inline short8 lds8(const us* p) {
  const uint2* q = (const uint2*)p;
  uint2 a = q[0], b = q[1];
  union { unsigned u[4]; short8 v; } t;
  t.u[0] = a.x; t.u[1] = a.y; t.u[2] = b.x; t.u[3] = b.y;
  return t.v;
}

// ---------------------------------------------------------------------------
// bf16x3 MFMA NT GEMM. 64x64 block tile, 4 waves (one 32x32 quadrant each),
// 3 accumulator chains. Double-buffered LDS + 2-iteration-deep register
// prefetch (load for iter i+2 issued at iter i -> ~1500cyc slack > HBM 900).
// M,N mult of 64; K mult of 32 (K>=64).
// ---------------------------------------------------------------------------
__global__ __launch_bounds__(256) void mfma_nt(
    const us* __restrict__ Ah, const us* __restrict__ Al, int lda,
    const us* __restrict__ Bh, const us* __restrict__ Bl,
    const float* __restrict__ bias,
    float* __restrict__ Cf, int ldc,
    us* __restrict__ Ch, us* __restrict__ Cl, int ldch,
    int K, int relu) {
  __shared__ us Ash[2][64][36], Asl[2][64][36], Bsh[2][64][36], Bsl[2][64][36];
  const int tid = threadIdx.x;
  const int bm = blockIdx.y * 64, bn = blockIdx.x * 64;
  const int wave = tid >> 6, lane = tid & 63;
  const int mh = (wave & 1) * 32, nh = (wave >> 1) * 32;
  const int l31 = lane & 31, hi5 = lane >> 5;
  const int srow = tid >> 2, skc = (tid & 3) * 8;
  const us* pAh = Ah + (size_t)(bm + srow) * lda + skc;
  const us* pAl = Al + (size_t)(bm + srow) * lda + skc;
  const us* pBh = Bh + (size_t)(bn + srow) * K + skc;
  const us* pBl = Bl + (size_t)(bn + srow) * K + skc;

  floatx16 acc_hh, acc_hl, acc_lh;
#pragma unroll
  for (int i = 0; i < 16; i++) { acc_hh[i] = 0.f; acc_hl[i] = 0.f; acc_lh[i] = 0.f; }

  uint4 qa[2], ql[2], qb[2], qm[2];
  qa[0] = *(const uint4*)pAh;        ql[0] = *(const uint4*)pAl;
  qb[0] = *(const uint4*)pBh;        qm[0] = *(const uint4*)pBl;
  qa[1] = *(const uint4*)(pAh + 32); ql[1] = *(const uint4*)(pAl + 32);
  qb[1] = *(const uint4*)(pBh + 32); qm[1] = *(const uint4*)(pBl + 32);

  const int iters = K >> 5;
  for (int it = 0; it < iters; ++it) {
    const int p = it & 1;
    *(uint2*)&Ash[p][srow][skc]     = make_uint2(qa[p].x, qa[p].y);
    *(uint2*)&Ash[p][srow][skc + 4] = make_uint2(qa[p].z, qa[p].w);
    *(uint2*)&Asl[p][srow][skc]     = make_uint2(ql[p].x, ql[p].y);
    *(uint2*)&Asl[p][srow][skc + 4] = make_uint2(ql[p].z, ql[p].w);
    *(uint2*)&Bsh[p][srow][skc]     = make_uint2(qb[p].x, qb[p].y);
    *(uint2*)&Bsh[p][srow][skc + 4] = make_uint2(qb[p].z, qb[p].w);
    *(uint2*)&Bsl[p][srow][skc]     = make_uint2(qm[p].x, qm[p].y);
    *(uint2*)&Bsl[p][srow][skc + 4] = make_uint2(qm[p].z, qm[p].w);
    __syncthreads();
    int it2 = it + 2;
    int kf = (it2 < iters ? it2 : it2 - iters) * 32;  // wrap: harmless refetch
    qa[p] = *(const uint4*)(pAh + kf);
    ql[p] = *(const uint4*)(pAl + kf);
    qb[p] = *(const uint4*)(pBh + kf);
    qm[p] = *(const uint4*)(pBl + kf);
#pragma unroll
    for (int ks = 0; ks < 32; ks += 16) {
      short8 fa_h = lds8(&Ash[p][mh + l31][ks + hi5 * 8]);
      short8 fa_l = lds8(&Asl[p][mh + l31][ks + hi5 * 8]);
      short8 fb_h = lds8(&Bsh[p][nh + l31][ks + hi5 * 8]);
      short8 fb_l = lds8(&Bsl[p][nh + l31][ks + hi5 * 8]);
      acc_hh = __builtin_amdgcn_mfma_f32_32x32x16_bf16(fa_h, fb_h, acc_hh, 0, 0, 0);
      acc_hl = __builtin_amdgcn_mfma_f32_32x32x16_bf16(fa_h, fb_l, acc_hl, 0, 0, 0);
      acc_lh = __builtin_amdgcn_mfma_f32_32x32x16_bf16(fa_l, fb_h, acc_lh, 0, 0, 0);
    }
  }
#pragma unroll
  for (int r = 0; r < 16; r++) {
    int m = bm + mh + (r & 3) + 8 * (r >> 2) + 4 * hi5;
    int n = bn + nh + l31;
    float v = acc_hh[r] + acc_hl[r] + acc_lh[r] + bias[n];
    if (relu) v = fmaxf(v, 0.f);
    if (Cf) Cf[(size_t)m * ldc + n] = v;
    if (Ch) {
      us hb = f2bf(v);
      Ch[(size_t)m * ldch + n] = hb;
      Cl[(size_t)m * ldch + n] = f2bf(v - bf2f(hb));
    }
  }
}

// ---------------------------------------------------------------------------
// logit GEMM: A pre-split (Hh,Hl) [Mtot x 768], B = proj_w1 split, K=N=768.
// Same 64x64 dbuf + 2-deep prefetch. Epilogue: relu(acc+b1[n])*w2[n],
// reduce over the 64-col n-tile, Lpart[ntile][m]. Grid (12, Mtot/64).
// ---------------------------------------------------------------------------
__global__ __launch_bounds__(256) void mfma_logit(
    const us* __restrict__ Ah, const us* __restrict__ Al,
    const us* __restrict__ Bh, const us* __restrict__ Bl,
    const float* __restrict__ b1, const float* __restrict__ w2,
    float* __restrict__ Lpart) {
  __shared__ us Ash[2][64][36], Asl[2][64][36], Bsh[2][64][36], Bsl[2][64][36];
  __shared__ float lpart[64];
  const int K = Dd;
  const int tid = threadIdx.x;
  const int bm = blockIdx.y * 64, bn = blockIdx.x * 64;
  const int wave = tid >> 6, lane = tid & 63;
  const int mh = (wave & 1) * 32, nh = (wave >> 1) * 32;
  const int l31 = lane & 31, hi5 = lane >> 5;
  const int srow = tid >> 2, skc = (tid & 3) * 8;
  const us* pAh = Ah + (size_t)(bm + srow) * K + skc;
  const us* pAl = Al + (size_t)(bm + srow) * K + skc;
  const us* pBh = Bh + (size_t)(bn + srow) * K + skc;
  const us* pBl = Bl + (size_t)(bn + srow) * K + skc;
  if (tid < 64) lpart[tid] = 0.f;

  floatx16 acc_hh, acc_hl, acc_lh;
#pragma unroll
  for (int i = 0; i < 16; i++) { acc_hh[i] = 0.f; acc_hl[i] = 0.f; acc_lh[i] = 0.f; }

  uint4 qa[2], ql[2], qb[2], qm[2];
  qa[0] = *(const uint4*)pAh;        ql[0] = *(const uint4*)pAl;
  qb[0] = *(const uint4*)pBh;        qm[0] = *(const uint4*)pBl;
  qa[1] = *(const uint4*)(pAh + 32); ql[1] = *(const uint4*)(pAl + 32);
  qb[1] = *(const uint4*)(pBh + 32); qm[1] = *(const uint4*)(pBl + 32);

  const int iters = K >> 5;
  for (int it = 0; it < iters; ++it) {
    const int p = it & 1;
    *(uint2*)&Ash[p][srow][skc]     = make_uint2(qa[p].x, qa[p].y);
    *(uint2*)&Ash[p][srow][skc + 4] = make_uint2(qa[p].z, qa[p].w);
    *(uint2*)&Asl[p][srow][skc]     = make_uint2(ql[p].x, ql[p].y);
    *(uint2*)&Asl[p][srow][skc + 4] = make_uint2(ql[p].z, ql[p].w);
    *(uint2*)&Bsh[p][srow][skc]     = make_uint2(qb[p].x, qb[p].y);
    *(uint2*)&Bsh[p][srow][skc + 4] = make_uint2(qb[p].z, qb[p].w);
    *(uint2*)&Bsl[p][srow][skc]     = make_uint2(qm[p].x, qm[p].y);
    *(uint2*)&Bsl[p][srow][skc + 4] = make_uint2(qm[p].z, qm[p].w);
    __syncthreads();
    int it2 = it + 2;
    int kf = (it2 < iters ? it2 : it2 - iters) * 32;
    qa[p] = *(const uint4*)(pAh + kf);
    ql[p] = *(const uint4*)(pAl + kf);
    qb[p] = *(const uint4*)(pBh + kf);
    qm[p] = *(const uint4*)(pBl + kf);
#pragma unroll
    for (int ks = 0; ks < 32; ks += 16) {
      short8 fa_h = lds8(&Ash[p][mh + l31][ks + hi5 * 8]);
      short8 fa_l = lds8(&Asl[p][mh + l31][ks + hi5 * 8]);
      short8 fb_h = lds8(&Bsh[p][nh + l31][ks + hi5 * 8]);
      short8 fb_l = lds8(&Bsl[p][nh + l31][ks + hi5 * 8]);
      acc_hh = __builtin_amdgcn_mfma_f32_32x32x16_bf16(fa_h, fb_h, acc_hh, 0, 0, 0);
      acc_hl = __builtin_amdgcn_mfma_f32_32x32x16_bf16(fa_h, fb_l, acc_hl, 0, 0, 0);
      acc_lh = __builtin_amdgcn_mfma_f32_32x32x16_bf16(fa_l, fb_h, acc_lh, 0, 0, 0);
    }
  }
  int n = bn + nh + l31;
  float bn1 = b1[n], wn = w2[n];
#pragma unroll
  for (int r = 0; r < 16; r++) {
    int mloc = mh + (r & 3) + 8 * (r >> 2) + 4 * hi5;
    float v = acc_hh[r] + acc_hl[r] + acc_lh[r] + bn1;
    v = fmaxf(v, 0.f) * wn;
    v += __shfl_xor(v, 1);
    v += __shfl_xor(v, 2);
    v += __shfl_xor(v, 4);
    v += __shfl_xor(v, 8);
    v += __shfl_xor(v, 16);
    if (l31 == 0) atomicAdd(&lpart[mloc], v);
  }
  __syncthreads();
  if (tid < 64) Lpart[(size_t)blockIdx.x * Mtot + bm + tid] = lpart[tid];
}

// ---------------------------------------------------------------------------
// scalar f32 NT GEMM (tiny M: question, gh0)
// ---------------------------------------------------------------------------
__global__ __launch_bounds__(256) void gemm_s(const float* __restrict__ A,
                                              const float* __restrict__ Bw,
                                              const float* __restrict__ bias,
                                              float* __restrict__ C,
                                              int M, int N, int K,
                                              int lda, int ldc, int relu) {
  __shared__ float As[16][65];
  __shared__ float Bs[16][65];
  int bm = blockIdx.y * 64, bn = blockIdx.x * 64;
  int tid = threadIdx.x;
  int tx = tid & 15, ty = tid >> 4;
  float acc[4][4] = {};
  for (int k0 = 0; k0 < K; k0 += 16) {
#pragma unroll
    for (int i = 0; i < 4; i++) {
      int l = tid * 4 + i;
      int row = l >> 4, kk = l & 15;
      float v = 0.f;
      if (bm + row < M) v = A[(size_t)(bm + row) * lda + k0 + kk];
      As[kk][row] = v;
    }
#pragma unroll
    for (int i = 0; i < 4; i++) {
      int l = tid * 4 + i;
      int row = l >> 4, kk = l & 15;
      float v = 0.f;
      if (bn + row < N) v = Bw[(size_t)(bn + row) * K + k0 + kk];
      Bs[kk][row] = v;
    }
    __syncthreads();
#pragma unroll
    for (int kk = 0; kk < 16; kk++) {
      float a4[4], b4[4];
#pragma unroll
      for (int i = 0; i < 4; i++) a4[i] = As[kk][ty * 4 + i];
#pragma unroll
      for (int j = 0; j < 4; j++) b4[j] = Bs[kk][tx * 4 + j];
#pragma unroll
      for (int i = 0; i < 4; i++)
#pragma unroll
        for (int j = 0; j < 4; j++) acc[i][j] += a4[i] * b4[j];
    }
    __syncthreads();
  }
#pragma unroll
  for (int i = 0; i < 4; i++) {
    int m = bm + ty * 4 + i;
    if (m >= M) continue;
#pragma unroll
    for (int j = 0; j < 4; j++) {
      int n = bn + tx * 4 + j;
      if (n >= N) continue;
      float v = acc[i][j] + bias[n];
      if (relu) v = fmaxf(v, 0.f);
      C[(size_t)m * ldc + n] = v;
    }
  }
}

// ---------------------------------------------------------------------------
// attention (f32), float4-vectorized LDS
// ---------------------------------------------------------------------------
__global__ __launch_bounds__(256) void att_qk(const float* __restrict__ qp,
                                              const float* __restrict__ kp,
                                              float* __restrict__ Sout,
                                              int Tq, int Tk, int kdiv, int ldk,
                                              float scale) {
  int g = blockIdx.x;
  int h = g % NH;
  int qrow0 = (g / NH) * Tq;
  int krow0 = (g / (NH * kdiv)) * Tk;
  int q0 = blockIdx.y * 32;
  int k0 = blockIdx.z * 64;
  __shared__ float Qs[32][68];
  __shared__ float KsT[64][72];   // transposed: [d][k]
  int tid = threadIdx.x;
  {
    int row = tid >> 3, db = (tid & 7) * 8;
    int qr = q0 + row;
    float4 v0 = {0, 0, 0, 0}, v1 = {0, 0, 0, 0};
    if (qr < Tq) {
      const float* p = qp + (size_t)(qrow0 + qr) * Dd + h * DHd + db;
      v0 = *(const float4*)p;
      v1 = *(const float4*)(p + 4);
    }
    *(float4*)&Qs[row][db] = v0;
    *(float4*)&Qs[row][db + 4] = v1;
  }
#pragma unroll
  for (int half = 0; half < 2; half++) {
    int row = (tid >> 3) + half * 32, db = (tid & 7) * 8;
    int kr = k0 + row;
    float4 v0 = {0, 0, 0, 0}, v1 = {0, 0, 0, 0};
    if (kr < Tk) {
      const float* p = kp + (size_t)(krow0 + kr) * ldk + h * DHd + db;
      v0 = *(const float4*)p;
      v1 = *(const float4*)(p + 4);
    }
    KsT[db + 0][row] = v0.x; KsT[db + 1][row] = v0.y;
    KsT[db + 2][row] = v0.z; KsT[db + 3][row] = v0.w;
    KsT[db + 4][row] = v1.x; KsT[db + 5][row] = v1.y;
    KsT[db + 6][row] = v1.z; KsT[db + 7][row] = v1.w;
  }
  __syncthreads();
  int q = tid >> 3, kg = tid & 7;
  float acc[8] = {};
  for (int d = 0; d < DHd; d++) {
    float qv = Qs[q][d];
    float4 k0v = *(const float4*)&KsT[d][kg * 8];
    float4 k1v = *(const float4*)&KsT[d][kg * 8 + 4];
    acc[0] += qv * k0v.x; acc[1] += qv * k0v.y;
    acc[2] += qv * k0v.z; acc[3] += qv * k0v.w;
    acc[4] += qv * k1v.x; acc[5] += qv * k1v.y;
    acc[6] += qv * k1v.z; acc[7] += qv * k1v.w;
  }
  if (q0 + q < Tq) {
    size_t basep = ((size_t)g * Tq + q0 + q) * Tk + k0 + kg * 8;
#pragma unroll
    for (int j = 0; j < 8; j++) Sout[basep + j] = acc[j] * scale;
  }
}

// P@V with fused bf16-split output (Outh/Outl)
__global__ __launch_bounds__(256) void att_pv(const float* __restrict__ P,
                                              const float* __restrict__ vp,
                                              us* __restrict__ Outh,
                                              us* __restrict__ Outl,
                                              int Tq, int Tk, int kdiv, int ldv) {
  int g = blockIdx.x;
  int h = g % NH;
  int qrow0 = (g / NH) * Tq;
  int krow0 = (g / (NH * kdiv)) * Tk;
  int q0 = blockIdx.y * 32;
  __shared__ float Ps[32][68];
  __shared__ float Vs[64][72];
  int tid = threadIdx.x;
  int q = tid >> 3, dg = tid & 7;
  float acc[8] = {};
  for (int k0 = 0; k0 < Tk; k0 += 64) {
    {
      int row = tid >> 3, cb = (tid & 7) * 8;
      int qr = q0 + row;
      float4 v0 = {0, 0, 0, 0}, v1 = {0, 0, 0, 0};
      if (qr < Tq) {
        const float* p = P + ((size_t)g * Tq + qr) * Tk + k0 + cb;
        v0 = *(const float4*)p;
        v1 = *(const float4*)(p + 4);
      }
      *(float4*)&Ps[row][cb] = v0;
      *(float4*)&Ps[row][cb + 4] = v1;
    }
#pragma unroll
    for (int half = 0; half < 2; half++) {
      int row = (tid >> 3) + half * 32, db = (tid & 7) * 8;
      const float* p = vp + (size_t)(krow0 + k0 + row) * ldv + h * DHd + db;
      *(float4*)&Vs[row][db] = *(const float4*)p;
      *(float4*)&Vs[row][db + 4] = *(const float4*)(p + 4);
    }
    __syncthreads();
#pragma unroll 4
    for (int kk4 = 0; kk4 < 16; kk4++) {
      float4 pv = *(const float4*)&Ps[q][kk4 * 4];
      float pe[4] = {pv.x, pv.y, pv.z, pv.w};
#pragma unroll
      for (int e = 0; e < 4; e++) {
        int kk = kk4 * 4 + e;
        float4 v0 = *(const float4*)&Vs[kk][dg * 8];
        float4 v1 = *(const float4*)&Vs[kk][dg * 8 + 4];
        acc[0] += pe[e] * v0.x; acc[1] += pe[e] * v0.y;
        acc[2] += pe[e] * v0.z; acc[3] += pe[e] * v0.w;
        acc[4] += pe[e] * v1.x; acc[5] += pe[e] * v1.y;
        acc[6] += pe[e] * v1.z; acc[7] += pe[e] * v1.w;
      }
    }
    __syncthreads();
  }
  if (q0 + q < Tq) {
    size_t basep = (size_t)(qrow0 + q0 + q) * Dd + h * DHd + dg * 8;
    union { us u[8]; uint4 v; } ph, pl;
#pragma unroll
    for (int j = 0; j < 8; j++) {
      us hb = f2bf(acc[j]);
      ph.u[j] = hb;
      pl.u[j] = f2bf(acc[j] - bf2f(hb));
    }
    *(uint4*)&Outh[basep] = ph.v;
    *(uint4*)&Outl[basep] = pl.v;
  }
}

__global__ __launch_bounds__(256) void softmax_rows(float* __restrict__ X, int len) {
  int row = blockIdx.x;
  float* p = X + (size_t)row * len;
  int tid = threadIdx.x;
  __shared__ float red[4];
  __shared__ float red2[4];
  float lmax = -1e30f;
  for (int j = tid; j < len; j += 256) lmax = fmaxf(lmax, p[j]);
  for (int off = 32; off; off >>= 1) lmax = fmaxf(lmax, __shfl_down(lmax, off));
  if ((tid & 63) == 0) red[tid >> 6] = lmax;
  __syncthreads();
  if (tid == 0) red[0] = fmaxf(fmaxf(red[0], red[1]), fmaxf(red[2], red[3]));
  __syncthreads();
  float m = red[0];
  float lsum = 0.f;
  for (int j = tid; j < len; j += 256) {
    float e = expf(p[j] - m);
    p[j] = e;
    lsum += e;
  }
  for (int off = 32; off; off >>= 1) lsum += __shfl_down(lsum, off);
  if ((tid & 63) == 0) red2[tid >> 6] = lsum;
  __syncthreads();
  if (tid == 0) red2[0] = red2[0] + red2[1] + red2[2] + red2[3];
  __syncthreads();
  float inv = 1.f / red2[0];
  for (int j = tid; j < len; j += 256) p[j] *= inv;
}

// fused head-mean + qv = W @ vatt -> cat slice [0,D)
__global__ __launch_bounds__(256) void qv2_k(const float* __restrict__ S2,
                                             const float* __restrict__ vatt,
                                             us* __restrict__ ch, us* __restrict__ cl) {
  int row = blockIdx.x;
  int b = row / (NST * An);
  int bs = row / An;
  int a = row % An;
  __shared__ float wm[TSn];
  int tid = threadIdx.x;
  if (tid < TSn) {
    float acc = 0.f;
    for (int h = 0; h < NH; h++)
      acc += S2[(((size_t)bs * NH + h) * An + a) * TSn + tid];
    wm[tid] = acc * (1.f / NH);
  }
  __syncthreads();
  for (int j = tid; j < Dd; j += 256) {
    float acc = 0.f;
    for (int k = 0; k < TSn; k++)
      acc += wm[k] * vatt[((size_t)b * TSn + k) * Dd + j];
    size_t o = (size_t)row * DPn + j;
    us hb = f2bf(acc);
    ch[o] = hb;
    cl[o] = f2bf(acc - bf2f(hb));
  }
}

// qa = qf[b] + at[row] -> cat slice [2D,3D)
__global__ void qa_add(const float* __restrict__ qf, const float* __restrict__ at,
                       us* __restrict__ ch, us* __restrict__ cl) {
  int idx = blockIdx.x * 256 + threadIdx.x;
  if (idx >= Bn * NST * An * Dd) return;
  int b = idx / (NST * An * Dd);
  int row = idx / Dd;
  int j = idx % Dd;
  float v = qf[b * Dd + j] + at[idx];
  size_t o = (size_t)row * DPn + 2 * Dd + j;
  us hb = f2bf(v);
  ch[o] = hb;
  cl[o] = f2bf(v - bf2f(hb));
}

// ---------------------------------------------------------------------------
// GRU combine for ALL candidate rows; float4-vectorized; pre-split output.
// Row layout: [0,128): s=0 rows (b,a). [128,Mtot): 128+(((b*7+s-1)*16+a)*16+c).
// ---------------------------------------------------------------------------
__global__ void combine_all(const float* __restrict__ gi,
                            const float* __restrict__ ghALL,
                            const float* __restrict__ gh0,
                            const float* __restrict__ inps,
                            const float* __restrict__ state0,
                            us* __restrict__ Hh, us* __restrict__ Hl) {
  const int D4 = Dd / 4;
  int idx = blockIdx.x * 256 + threadIdx.x;
  if (idx >= Mtot * D4) return;
  int row = idx / D4, j = (idx - row * D4) * 4;
  const float* gp;
  const float* ghp;
  const float* stp;
  if (row < 128) {
    int b = row >> 4, a = row & 15;
    gp = gi + ((size_t)(b * NST) * An + a) * GSn;
    ghp = gh0;
    stp = state0;
  } else {
    int r = row - 128;
    int c = r & 15; r >>= 4;
    int a = r & 15; r >>= 4;
    int sm1 = r % 7, b = r / 7;
    size_t prev = (size_t)(b * NST + sm1) * An + c;
    gp = gi + ((size_t)(b * NST + sm1 + 1) * An + a) * GSn;
    ghp = ghALL + prev * GSn;
    stp = inps + prev * Dd;
  }
  float4 ir4 = *(const float4*)(gp + j);
  float4 iz4 = *(const float4*)(gp + Dd + j);
  float4 in4 = *(const float4*)(gp + 2 * Dd + j);
  float4 hr4 = *(const float4*)(ghp + j);
  float4 hz4 = *(const float4*)(ghp + Dd + j);
  float4 hn4 = *(const float4*)(ghp + 2 * Dd + j);
  float4 st4 = *(const float4*)(stp + j);
  float ir[4] = {ir4.x, ir4.y, ir4.z, ir4.w};
  float iz[4] = {iz4.x, iz4.y, iz4.z, iz4.w};
  float in_[4] = {in4.x, in4.y, in4.z, in4.w};
  float hr[4] = {hr4.x, hr4.y, hr4.z, hr4.w};
  float hz[4] = {hz4.x, hz4.y, hz4.z, hz4.w};
  float hn[4] = {hn4.x, hn4.y, hn4.z, hn4.w};
  float st[4] = {st4.x, st4.y, st4.z, st4.w};
  union { us u[4]; uint2 w; } oh, ol;
#pragma unroll
  for (int t = 0; t < 4; t++) {
    float rg = 1.f / (1.f + expf(-(ir[t] + hr[t])));
    float zg = 1.f / (1.f + expf(-(iz[t] + hz[t])));
    float ng = tanhf(in_[t] + rg * hn[t]);
    float v = (1.f - zg) * ng + zg * st[t];
    us hb = f2bf(v);
    oh.u[t] = hb;
    ol.u[t] = f2bf(v - bf2f(hb));
  }
  *(uint2*)&Hh[(size_t)row * Dd + j] = oh.w;
  *(uint2*)&Hl[(size_t)row * Dd + j] = ol.w;
}

// ---------------------------------------------------------------------------
// pick: walk the argmax chain over logit partials (12 n-tiles).
// ---------------------------------------------------------------------------
__global__ __launch_bounds__(64) void pick_k(const float* __restrict__ Lpart,
                                             const float* __restrict__ b2v,
                                             float* __restrict__ out) {
  int b = blockIdx.x;
  int lane = threadIdx.x;
  int c = 0;
  float b2 = b2v[0];
  for (int s = 0; s < NST; s++) {
    int row;
    if (s == 0) row = b * 16 + (lane & 15);
    else row = 128 + (((b * 7 + (s - 1)) * 16 + (lane & 15)) * 16 + c);
    float v = 0.f;
#pragma unroll
    for (int t = 0; t < 12; t++) v += Lpart[(size_t)t * Mtot + row];
    v += b2;
    if (lane < 16) out[(size_t)(b * NST + s) * An + lane] = v;
    float bv = (lane < 16) ? v : -1e30f;
    int bi = (lane < 16) ? lane : 999;
#pragma unroll
    for (int off = 1; off < 16; off <<= 1) {
      float ov = __shfl_xor(bv, off);
      int oi = __shfl_xor(bi, off);
      if (ov > bv || (ov == bv && oi < bi)) { bv = ov; bi = oi; }
    }
    c = __shfl(bi, 0);
  }
}

// ---------------------------------------------------------------------------
static inline void mm(const us* Ah, const us* Al, int lda, const us* Bh, const us* Bl,
                      const float* bias, float* Cf, int ldc, us* Ch, us* Cl, int ldch,
                      int M, int N, int K, int relu, hipStream_t st) {
  dim3 g(N / 64, M / 64);
  mfma_nt<<<g, 256, 0, st>>>(Ah, Al, lda, Bh, Bl, bias, Cf, ldc, Ch, Cl, ldch, K, relu);
}
static inline void sgemm(const float* A, const float* W, const float* bias, float* C,
                         int M, int N, int K, int lda, int ldc, int relu, hipStream_t st) {
  dim3 g((N + 63) / 64, (M + 63) / 64);
  gemm_s<<<g, 256, 0, st>>>(A, W, bias, C, M, N, K, lda, ldc, relu);
}
static inline void split(const float* x, us* h, us* l, int n, hipStream_t st) {
  int n4 = n >> 2;
  int blocks = (n4 + 255) / 256;
  if (blocks > 2048) blocks = 2048;
  split_k<<<blocks, 256, 0, st>>>(x, h, l, n4);
}

extern "C" void kernel_launch(void* const* d_in, const int* in_sizes, int n_in,
                              void* d_out, int out_size, void* d_ws, size_t ws_size,
                              hipStream_t stream) {
  const float* video     = (const float*)d_in[0];
  const float* script    = (const float*)d_in[1];
  const float* question  = (const float*)d_in[2];
  const float* a_texts   = (const float*)d_in[3];
  const float* a_buttons = (const float*)d_in[4];
  const float* v_w1 = (const float*)d_in[5];
  const float* v_b1 = (const float*)d_in[6];
  const float* v_w2 = (const float*)d_in[7];
  const float* v_b2 = (const float*)d_in[8];
  const float* t_w1 = (const float*)d_in[9];
  const float* t_b1 = (const float*)d_in[10];
  const float* t_w2 = (const float*)d_in[11];
  const float* t_b2 = (const float*)d_in[12];
  const float* pre_w1 = (const float*)d_in[13];
  const float* pre_b1 = (const float*)d_in[14];
  const float* pre_w2 = (const float*)d_in[15];
  const float* pre_b2 = (const float*)d_in[16];
  const float* s2v_win  = (const float*)d_in[17];
  const float* s2v_bin  = (const float*)d_in[18];
  const float* s2v_wout = (const float*)d_in[19];
  const float* s2v_bout = (const float*)d_in[20];
  const float* qa_win  = (const float*)d_in[21];
  const float* qa_bin  = (const float*)d_in[22];
  const float* qa_wout = (const float*)d_in[23];
  const float* qa_bout = (const float*)d_in[24];
  const float* gru_wih = (const float*)d_in[25];
  const float* gru_whh = (const float*)d_in[26];
  const float* gru_bih = (const float*)d_in[27];
  const float* gru_bhh = (const float*)d_in[28];
  const float* proj_w1 = (const float*)d_in[29];
  const float* proj_b1 = (const float*)d_in[30];
  const float* proj_w2 = (const float*)d_in[31];
  const float* proj_b2 = (const float*)d_in[32];
  const float* state0  = (const float*)d_in[33];
  (void)in_sizes; (void)n_in; (void)out_size; (void)ws_size;

  constexpr int W589  = 768 * 768;
  constexpr int W1769 = 2304 * 768;
  constexpr int W9437 = 3072 * 3072;
  constexpr int W2359 = 768 * 3072;
  constexpr int SMe   = 1024 * 768;
  constexpr int BIGe  = 4096 * 768;

  char* base = (char*)d_ws;
  char* RW1 = base;                   // 9,437,184 : phase-A weights -> ghALL
  char* RW2 = RW1 + 9437184;          // 9,437,184 : s2v/qa/pre_w2 weights -> gi
  char* R1  = RW2 + 9437184;          // 28,311,552
  char* R2  = R1 + 28311552;          // 12,582,912
  char* X   = R2 + 12582912;          // 25,165,824
  char* P   = X + 25165824;           // ~20 MB persistents

  us* vw1h = (us*)RW1;        us* vw1l = vw1h + W589;
  us* vw2h = vw1l + W589;     us* vw2l = vw2h + W589;
  us* tw1h = vw2l + W589;     us* tw1l = tw1h + W589;
  us* tw2h = tw1l + W589;     us* tw2l = tw2h + W589;
  float* ghALL = (float*)RW1;           // after phase-A weights dead
  us* s2vwh = (us*)RW2;       us* s2vwl = s2vwh + W1769;
  us* s2voh = s2vwl + W1769;  us* s2vol = s2voh + W589;
  us* qawh  = (us*)RW2;       us* qawl  = qawh + W1769;
  us* qaoh  = qawl + W1769;   us* qaol  = qaoh + W589;
  us* pw2h  = (us*)RW2;       us* pw2l  = pw2h + W2359;
  float* gi = (float*)RW2;              // after pw2 dead
  us* vidh = (us*)R1;         us* vidl = vidh + BIGe;
  us* hidh = vidl + BIGe;     us* hidl = hidh + BIGe;
  us* scrh = (us*)R1;         us* scrl = scrh + SMe;
  float* kvproj = (float*)R1;
  float* qproj  = kvproj + (size_t)4096 * 1536;
  float* kv2 = (float*)R1;
  float* qp2 = (float*)(R1 + 6291456);
  float* S2  = (float*)(R1 + 9437184);
  us* abhh = (us*)(R1 + 15728640); us* abhl = abhh + SMe;
  us* pw1h = (us*)R1;         us* pw1l = pw1h + W9437;
  us* gwihh = (us*)R1;        us* gwihl = gwihh + W1769;
  us* pjw1h = (us*)(R1 + 7077888);  us* pjw1l = pjw1h + W589;
  us* gwhhh = (us*)(R1 + 9437184);  us* gwhhl = gwhhh + W1769;
  us* vh = (us*)R2;           us* vl = vh + BIGe;
  us* aoh = (us*)(R2 + 3145728); us* aol = aoh + SMe;
  // candidate matrix (pre-split): spans R2+X and the dead prefix of P
  us* Hh = (us*)R2;           us* Hl = Hh + (size_t)Mtot * Dd;
  float* S1 = (float*)X;
  us* cath = (us*)X;          us* catl = cath + (size_t)1024 * DPn;
  us* prehh = (us*)(X + 12582912); us* prehl = prehh + (size_t)1024 * DPn;
  us* abinh = (us*)P;         us* abinl = abinh + SMe;
  us* sch   = (us*)(P + 3145728); us* scl = sch + SMe;
  float* at_f   = (float*)(P + 6291456);
  float* vatt   = (float*)(P + 9437184);
  float* inps_f = (float*)(P + 12582912);
  us* inpsh = (us*)(P + 15728640); us* inpsl = inpsh + SMe;
  float* qf    = (float*)(P + 18874368);
  float* qhid  = (float*)(P + 18898944);
  float* gh0   = (float*)(P + 18923520);
  float* Lpart = (float*)(P + 18932736);   // 12 x 14464 f32

  // ---- phase A ----
  split4_k<<<dim3(1024, 4), 256, 0, stream>>>(v_w1, vw1h, vw1l, W589,
                                              v_w2, vw2h, vw2l, W589,
                                              t_w1, tw1h, tw1l, W589,
                                              t_w2, tw2h, tw2l, W589);
  split(video, vidh, vidl, BIGe, stream);
  mm(vidh, vidl, Dd, vw1h, vw1l, v_b1, nullptr, 0, hidh, hidl, Dd, 4096, Dd, Dd, 1, stream);
  mm(hidh, hidl, Dd, vw2h, vw2l, v_b2, nullptr, 0, vh, vl, Dd, 4096, Dd, Dd, 0, stream);
  split(script, scrh, scrl, SMe, stream);
  mm(scrh, scrl, Dd, tw1h, tw1l, t_b1, nullptr, 0, hidh, hidl, Dd, 1024, Dd, Dd, 1, stream);
  mm(hidh, hidl, Dd, tw2h, tw2l, t_b2, nullptr, 0, sch, scl, Dd, 1024, Dd, Dd, 0, stream);
  sgemm(question, t_w1, t_b1, qhid, Bn, Dd, Dd, Dd, Dd, 1, stream);
  sgemm(qhid, t_w2, t_b2, qf, Bn, Dd, Dd, Dd, Dd, 0, stream);
  split(a_texts, scrh, scrl, SMe, stream);
  mm(scrh, scrl, Dd, tw1h, tw1l, t_b1, nullptr, 0, hidh, hidl, Dd, 1024, Dd, Dd, 1, stream);
  mm(hidh, hidl, Dd, tw2h, tw2l, t_b2, at_f, Dd, nullptr, nullptr, 0, 1024, Dd, Dd, 0, stream);
  split(a_buttons, abinh, abinl, SMe, stream);

  // ---- s2v attention (K/V merged: N=1536) ----
  split4_k<<<dim3(1024, 4), 256, 0, stream>>>(s2v_win, s2vwh, s2vwl, W1769,
                                              s2v_wout, s2voh, s2vol, W589,
                                              nullptr, nullptr, nullptr, 0,
                                              nullptr, nullptr, nullptr, 0);
  mm(vh, vl, Dd, s2vwh + (size_t)Dd * Dd, s2vwl + (size_t)Dd * Dd, s2v_bin + Dd,
     kvproj, 1536, nullptr, nullptr, 0, 4096, 1536, Dd, 0, stream);
  mm(sch, scl, Dd, s2vwh, s2vwl, s2v_bin, qproj, Dd, nullptr, nullptr, 0, 1024, Dd, Dd, 0, stream);
  att_qk<<<dim3(Bn * NH, TSn / 32, TVn / 64), 256, 0, stream>>>(qproj, kvproj, S1,
                                                                TSn, TVn, 1, 1536, 0.125f);
  softmax_rows<<<Bn * NH * TSn, 256, 0, stream>>>(S1, TVn);
  att_pv<<<dim3(Bn * NH, TSn / 32), 256, 0, stream>>>(S1, kvproj + Dd, aoh, aol,
                                                      TSn, TVn, 1, 1536);
  mm(aoh, aol, Dd, s2voh, s2vol, s2v_bout, vatt, Dd, nullptr, nullptr, 0, 1024, Dd, Dd, 0, stream);

  // ---- phase B: ab MLP, qa attention ----
  mm(abinh, abinl, Dd, vw1h, vw1l, v_b1, nullptr, 0, abhh, abhl, Dd, 1024, Dd, Dd, 1, stream);
  mm(abhh, abhl, Dd, vw2h, vw2l, v_b2, nullptr, 0, cath + 3 * Dd, catl + 3 * Dd, DPn,
     1024, Dd, Dd, 0, stream);
  qa_add<<<(1024 * Dd + 255) / 256, 256, 0, stream>>>(qf, at_f, cath, catl);
  split4_k<<<dim3(1024, 4), 256, 0, stream>>>(qa_win, qawh, qawl, W1769,
                                              qa_wout, qaoh, qaol, W589,
                                              nullptr, nullptr, nullptr, 0,
                                              nullptr, nullptr, nullptr, 0);
  mm(sch, scl, Dd, qawh + (size_t)Dd * Dd, qawl + (size_t)Dd * Dd, qa_bin + Dd,
     kv2, 1536, nullptr, nullptr, 0, 1024, 1536, Dd, 0, stream);
  mm(cath + 2 * Dd, catl + 2 * Dd, DPn, qawh, qawl, qa_bin, qp2, Dd, nullptr, nullptr, 0,
     1024, Dd, Dd, 0, stream);
  att_qk<<<dim3(Bn * NST * NH, 1, TSn / 64), 256, 0, stream>>>(qp2, kv2, S2,
                                                               An, TSn, NST, 1536, 0.125f);
  softmax_rows<<<Bn * NST * NH * An, 256, 0, stream>>>(S2, TSn);
  att_pv<<<dim3(Bn * NST * NH, 1), 256, 0, stream>>>(S2, kv2 + Dd, aoh, aol,
                                                     An, TSn, NST, 1536);
  mm(aoh, aol, Dd, qaoh, qaol, qa_bout, nullptr, 0, cath + Dd, catl + Dd, DPn,
     1024, Dd, Dd, 0, stream);
  qv2_k<<<1024, 256, 0, stream>>>(S2, vatt, cath, catl);

  // ---- pre-MLP + GRU gates ----
  split(pre_w1, pw1h, pw1l, W9437, stream);
  mm(cath, catl, DPn, pw1h, pw1l, pre_b1, nullptr, 0, prehh, prehl, DPn,
     1024, DPn, DPn, 1, stream);
  split4_k<<<dim3(1024, 4), 256, 0, stream>>>(pre_w2, pw2h, pw2l, W2359,
                                              gru_wih, gwihh, gwihl, W1769,
                                              gru_whh, gwhhh, gwhhl, W1769,
                                              proj_w1, pjw1h, pjw1l, W589);
  mm(prehh, prehl, DPn, pw2h, pw2l, pre_b2, inps_f, Dd, inpsh, inpsl, Dd,
     1024, Dd, DPn, 0, stream);
  mm(inpsh, inpsl, Dd, gwihh, gwihl, gru_bih, gi, GSn, nullptr, nullptr, 0,
     1024, GSn, Dd, 0, stream);
  mm(inpsh, inpsl, Dd, gwhhh, gwhhl, gru_bhh, ghALL, GSn, nullptr, nullptr, 0,
     1024, GSn, Dd, 0, stream);
  sgemm(state0, gru_whh, gru_bhh, gh0, 1, GSn, Dd, Dd, GSn, 0, stream);

  // ---- candidate enumeration + logits + argmax chain ----
  combine_all<<<(Mtot * (Dd / 4) + 255) / 256, 256, 0, stream>>>(gi, ghALL, gh0, inps_f,
                                                                 state0, Hh, Hl);
  mfma_logit<<<dim3(Dd / 64, Mtot / 64), 256, 0, stream>>>(Hh, Hl, pjw1h, pjw1l,
                                                           proj_b1, proj_w2, Lpart);
  pick_k<<<Bn, 64, 0, stream>>>(Lpart, proj_b2, (float*)d_out);
}

// Round 10
// 2031.538 us; speedup vs baseline: 1.0827x; 1.0827x over previous
//
#include <hip/hip_runtime.h>
#include <hip/hip_bf16.h>
#include <math.h>

constexpr int Dd  = 768;
constexpr int NH  = 12;
constexpr int DHd = 64;
constexpr int Bn  = 8;
constexpr int TVn = 512;
constexpr int TSn = 128;
constexpr int NST = 8;
constexpr int An  = 16;
constexpr int DPn = 3072;
constexpr int GSn = 2304;
constexpr int Mtot = 14464;   // 128 (s=0) + 8*7*16*16 candidate rows; 226*64

typedef unsigned short us;
using short8   = __attribute__((ext_vector_type(8))) short;
using floatx16 = __attribute__((ext_vector_type(16))) float;

__device__ inline us f2bf(float x) {
  union { float f; unsigned u; } a; a.f = x;
  return (us)((a.u + 0x7fffu + ((a.u >> 16) & 1u)) >> 16);
}
__device__ inline float bf2f(us h) {
  union { unsigned u; float f; } a; a.u = ((unsigned)h) << 16;
  return a.f;
}

// ---------------------------------------------------------------------------
// splits (float4-vectorized; n4 = n/4)
// ---------------------------------------------------------------------------
__global__ void split_k(const float* __restrict__ x, us* __restrict__ h,
                        us* __restrict__ l, int n4) {
  for (int i = blockIdx.x * 256 + threadIdx.x; i < n4; i += gridDim.x * 256) {
    float4 v = ((const float4*)x)[i];
    float vv[4] = {v.x, v.y, v.z, v.w};
    union { us u[4]; uint2 w; } hh, ll;
#pragma unroll
    for (int t = 0; t < 4; t++) {
      us hb = f2bf(vv[t]);
      hh.u[t] = hb;
      ll.u[t] = f2bf(vv[t] - bf2f(hb));
    }
    ((uint2*)h)[i] = hh.w;
    ((uint2*)l)[i] = ll.w;
  }
}

__global__ void split4_k(const float* s0, us* h0, us* l0, int n0,
                         const float* s1, us* h1, us* l1, int n1,
                         const float* s2, us* h2, us* l2, int n2,
                         const float* s3, us* h3, us* l3, int n3) {
  const float* s; us* h; us* l; int n;
  switch (blockIdx.y) {
    case 0: s = s0; h = h0; l = l0; n = n0; break;
    case 1: s = s1; h = h1; l = l1; n = n1; break;
    case 2: s = s2; h = h2; l = l2; n = n2; break;
    default: s = s3; h = h3; l = l3; n = n3; break;
  }
  int n4 = n >> 2;
  for (int i = blockIdx.x * 256 + threadIdx.x; i < n4; i += gridDim.x * 256) {
    float4 v = ((const float4*)s)[i];
    float vv[4] = {v.x, v.y, v.z, v.w};
    union { us u[4]; uint2 w; } hh, ll;
#pragma unroll
    for (int t = 0; t < 4; t++) {
      us hb = f2bf(vv[t]);
      hh.u[t] = hb;
      ll.u[t] = f2bf(vv[t] - bf2f(hb));
    }
    ((uint2*)h)[i] = hh.w;
    ((uint2*)l)[i] = ll.w;
  }
}

__device__ inline short8 lds8(const us* p) {
  const uint2* q = (const uint2*)p;
  uint2 a = q[0], b = q[1];
  union { unsigned u[4]; short8 v; } t;
  t.u[0] = a.x; t.u[1] = a.y; t.u[2] = b.x; t.u[3] = b.y;
  return t.v;
}

#define STORE_TILE(buf, A, L, B, M)                                   \
  *(uint2*)&Ash[buf][srow][skc]     = make_uint2((A).x, (A).y);       \
  *(uint2*)&Ash[buf][srow][skc + 4] = make_uint2((A).z, (A).w);       \
  *(uint2*)&Asl[buf][srow][skc]     = make_uint2((L).x, (L).y);       \
  *(uint2*)&Asl[buf][srow][skc + 4] = make_uint2((L).z, (L).w);       \
  *(uint2*)&Bsh[buf][srow][skc]     = make_uint2((B).x, (B).y);       \
  *(uint2*)&Bsh[buf][srow][skc + 4] = make_uint2((B).z, (B).w);       \
  *(uint2*)&Bsl[buf][srow][skc]     = make_uint2((M).x, (M).y);       \
  *(uint2*)&Bsl[buf][srow][skc + 4] = make_uint2((M).z, (M).w);

#define COMPUTE_TILE(buf)                                                          \
  _Pragma("unroll")                                                                \
  for (int ks = 0; ks < 32; ks += 16) {                                            \
    short8 fa_h = lds8(&Ash[buf][mh + l31][ks + hi5 * 8]);                         \
    short8 fa_l = lds8(&Asl[buf][mh + l31][ks + hi5 * 8]);                         \
    short8 fb_h = lds8(&Bsh[buf][nh + l31][ks + hi5 * 8]);                         \
    short8 fb_l = lds8(&Bsl[buf][nh + l31][ks + hi5 * 8]);                         \
    acc_hh = __builtin_amdgcn_mfma_f32_32x32x16_bf16(fa_h, fb_h, acc_hh, 0, 0, 0); \
    acc_hl = __builtin_amdgcn_mfma_f32_32x32x16_bf16(fa_h, fb_l, acc_hl, 0, 0, 0); \
    acc_lh = __builtin_amdgcn_mfma_f32_32x32x16_bf16(fa_l, fb_h, acc_lh, 0, 0, 0); \
  }

// ---------------------------------------------------------------------------
// bf16x3 MFMA NT GEMM. 64x64 block tile, 4 waves, 3 acc chains.
// Double-buffered LDS, unroll-by-2 K-loop with SCALAR prefetch registers
// (2-iteration depth). M,N mult of 64; K/32 EVEN (K=768/1536/3072 here).
// ---------------------------------------------------------------------------
__global__ __launch_bounds__(256) void mfma_nt(
    const us* __restrict__ Ah, const us* __restrict__ Al, int lda,
    const us* __restrict__ Bh, const us* __restrict__ Bl,
    const float* __restrict__ bias,
    float* __restrict__ Cf, int ldc,
    us* __restrict__ Ch, us* __restrict__ Cl, int ldch,
    int K, int relu) {
  __shared__ us Ash[2][64][36], Asl[2][64][36], Bsh[2][64][36], Bsl[2][64][36];
  const int tid = threadIdx.x;
  const int bm = blockIdx.y * 64, bn = blockIdx.x * 64;
  const int wave = tid >> 6, lane = tid & 63;
  const int mh = (wave & 1) * 32, nh = (wave >> 1) * 32;
  const int l31 = lane & 31, hi5 = lane >> 5;
  const int srow = tid >> 2, skc = (tid & 3) * 8;
  const us* pAh = Ah + (size_t)(bm + srow) * lda + skc;
  const us* pAl = Al + (size_t)(bm + srow) * lda + skc;
  const us* pBh = Bh + (size_t)(bn + srow) * K + skc;
  const us* pBl = Bl + (size_t)(bn + srow) * K + skc;

  floatx16 acc_hh, acc_hl, acc_lh;
#pragma unroll
  for (int i = 0; i < 16; i++) { acc_hh[i] = 0.f; acc_hl[i] = 0.f; acc_lh[i] = 0.f; }

  uint4 rA0 = *(const uint4*)pAh,        rL0 = *(const uint4*)pAl;
  uint4 rB0 = *(const uint4*)pBh,        rM0 = *(const uint4*)pBl;
  uint4 rA1 = *(const uint4*)(pAh + 32), rL1 = *(const uint4*)(pAl + 32);
  uint4 rB1 = *(const uint4*)(pBh + 32), rM1 = *(const uint4*)(pBl + 32);

  const int iters = K >> 5;   // even
  for (int it = 0; it < iters; it += 2) {
    STORE_TILE(0, rA0, rL0, rB0, rM0)
    __syncthreads();
    {
      int kf = (it + 2 < iters) ? (it + 2) * 32 : 0;
      rA0 = *(const uint4*)(pAh + kf);
      rL0 = *(const uint4*)(pAl + kf);
      rB0 = *(const uint4*)(pBh + kf);
      rM0 = *(const uint4*)(pBl + kf);
    }
    COMPUTE_TILE(0)
    STORE_TILE(1, rA1, rL1, rB1, rM1)
    __syncthreads();
    {
      int kf = (it + 3 < iters) ? (it + 3) * 32 : 32;
      rA1 = *(const uint4*)(pAh + kf);
      rL1 = *(const uint4*)(pAl + kf);
      rB1 = *(const uint4*)(pBh + kf);
      rM1 = *(const uint4*)(pBl + kf);
    }
    COMPUTE_TILE(1)
  }
#pragma unroll
  for (int r = 0; r < 16; r++) {
    int m = bm + mh + (r & 3) + 8 * (r >> 2) + 4 * hi5;
    int n = bn + nh + l31;
    float v = acc_hh[r] + acc_hl[r] + acc_lh[r] + bias[n];
    if (relu) v = fmaxf(v, 0.f);
    if (Cf) Cf[(size_t)m * ldc + n] = v;
    if (Ch) {
      us hb = f2bf(v);
      Ch[(size_t)m * ldch + n] = hb;
      Cl[(size_t)m * ldch + n] = f2bf(v - bf2f(hb));
    }
  }
}

// ---------------------------------------------------------------------------
// logit GEMM: A pre-split (Hh,Hl) [Mtot x 768], B = proj_w1 split, K=N=768.
// Same dbuf + scalar 2-deep prefetch. Epilogue: relu(acc+b1[n])*w2[n],
// reduce over the 64-col n-tile, Lpart[ntile][m]. Grid (12, Mtot/64).
// ---------------------------------------------------------------------------
__global__ __launch_bounds__(256) void mfma_logit(
    const us* __restrict__ Ah, const us* __restrict__ Al,
    const us* __restrict__ Bh, const us* __restrict__ Bl,
    const float* __restrict__ bias1, const float* __restrict__ w2,
    float* __restrict__ Lpart) {
  __shared__ us Ash[2][64][36], Asl[2][64][36], Bsh[2][64][36], Bsl[2][64][36];
  __shared__ float lpart[64];
  const int K = Dd;
  const int tid = threadIdx.x;
  const int bm = blockIdx.y * 64, bn = blockIdx.x * 64;
  const int wave = tid >> 6, lane = tid & 63;
  const int mh = (wave & 1) * 32, nh = (wave >> 1) * 32;
  const int l31 = lane & 31, hi5 = lane >> 5;
  const int srow = tid >> 2, skc = (tid & 3) * 8;
  const us* pAh = Ah + (size_t)(bm + srow) * K + skc;
  const us* pAl = Al + (size_t)(bm + srow) * K + skc;
  const us* pBh = Bh + (size_t)(bn + srow) * K + skc;
  const us* pBl = Bl + (size_t)(bn + srow) * K + skc;
  if (tid < 64) lpart[tid] = 0.f;

  floatx16 acc_hh, acc_hl, acc_lh;
#pragma unroll
  for (int i = 0; i < 16; i++) { acc_hh[i] = 0.f; acc_hl[i] = 0.f; acc_lh[i] = 0.f; }

  uint4 rA0 = *(const uint4*)pAh,        rL0 = *(const uint4*)pAl;
  uint4 rB0 = *(const uint4*)pBh,        rM0 = *(const uint4*)pBl;
  uint4 rA1 = *(const uint4*)(pAh + 32), rL1 = *(const uint4*)(pAl + 32);
  uint4 rB1 = *(const uint4*)(pBh + 32), rM1 = *(const uint4*)(pBl + 32);

  const int iters = K >> 5;   // 24
  for (int it = 0; it < iters; it += 2) {
    STORE_TILE(0, rA0, rL0, rB0, rM0)
    __syncthreads();
    {
      int kf = (it + 2 < iters) ? (it + 2) * 32 : 0;
      rA0 = *(const uint4*)(pAh + kf);
      rL0 = *(const uint4*)(pAl + kf);
      rB0 = *(const uint4*)(pBh + kf);
      rM0 = *(const uint4*)(pBl + kf);
    }
    COMPUTE_TILE(0)
    STORE_TILE(1, rA1, rL1, rB1, rM1)
    __syncthreads();
    {
      int kf = (it + 3 < iters) ? (it + 3) * 32 : 32;
      rA1 = *(const uint4*)(pAh + kf);
      rL1 = *(const uint4*)(pAl + kf);
      rB1 = *(const uint4*)(pBh + kf);
      rM1 = *(const uint4*)(pBl + kf);
    }
    COMPUTE_TILE(1)
  }
  int n = bn + nh + l31;
  float bn1 = bias1[n], wn = w2[n];
#pragma unroll
  for (int r = 0; r < 16; r++) {
    int mloc = mh + (r & 3) + 8 * (r >> 2) + 4 * hi5;
    float v = acc_hh[r] + acc_hl[r] + acc_lh[r] + bn1;
    v = fmaxf(v, 0.f) * wn;
    v += __shfl_xor(v, 1);
    v += __shfl_xor(v, 2);
    v += __shfl_xor(v, 4);
    v += __shfl_xor(v, 8);
    v += __shfl_xor(v, 16);
    if (l31 == 0) atomicAdd(&lpart[mloc], v);
  }
  __syncthreads();
  if (tid < 64) Lpart[(size_t)blockIdx.x * Mtot + bm + tid] = lpart[tid];
}

// ---------------------------------------------------------------------------
// scalar f32 NT GEMM (tiny M: question, gh0)
// ---------------------------------------------------------------------------
__global__ __launch_bounds__(256) void gemm_s(const float* __restrict__ A,
                                              const float* __restrict__ Bw,
                                              const float* __restrict__ bias,
                                              float* __restrict__ C,
                                              int M, int N, int K,
                                              int lda, int ldc, int relu) {
  __shared__ float As[16][65];
  __shared__ float Bs[16][65];
  int bm = blockIdx.y * 64, bn = blockIdx.x * 64;
  int tid = threadIdx.x;
  int tx = tid & 15, ty = tid >> 4;
  float acc[4][4] = {};
  for (int k0 = 0; k0 < K; k0 += 16) {
#pragma unroll
    for (int i = 0; i < 4; i++) {
      int l = tid * 4 + i;
      int row = l >> 4, kk = l & 15;
      float v = 0.f;
      if (bm + row < M) v = A[(size_t)(bm + row) * lda + k0 + kk];
      As[kk][row] = v;
    }
#pragma unroll
    for (int i = 0; i < 4; i++) {
      int l = tid * 4 + i;
      int row = l >> 4, kk = l & 15;
      float v = 0.f;
      if (bn + row < N) v = Bw[(size_t)(bn + row) * K + k0 + kk];
      Bs[kk][row] = v;
    }
    __syncthreads();
#pragma unroll
    for (int kk = 0; kk < 16; kk++) {
      float a4[4], b4[4];
#pragma unroll
      for (int i = 0; i < 4; i++) a4[i] = As[kk][ty * 4 + i];
#pragma unroll
      for (int j = 0; j < 4; j++) b4[j] = Bs[kk][tx * 4 + j];
#pragma unroll
      for (int i = 0; i < 4; i++)
#pragma unroll
        for (int j = 0; j < 4; j++) acc[i][j] += a4[i] * b4[j];
    }
    __syncthreads();
  }
#pragma unroll
  for (int i = 0; i < 4; i++) {
    int m = bm + ty * 4 + i;
    if (m >= M) continue;
#pragma unroll
    for (int j = 0; j < 4; j++) {
      int n = bn + tx * 4 + j;
      if (n >= N) continue;
      float v = acc[i][j] + bias[n];
      if (relu) v = fmaxf(v, 0.f);
      C[(size_t)m * ldc + n] = v;
    }
  }
}

// ---------------------------------------------------------------------------
// attention (f32), float4-vectorized LDS
// ---------------------------------------------------------------------------
__global__ __launch_bounds__(256) void att_qk(const float* __restrict__ qp,
                                              const float* __restrict__ kp,
                                              float* __restrict__ Sout,
                                              int Tq, int Tk, int kdiv, int ldk,
                                              float scale) {
  int g = blockIdx.x;
  int h = g % NH;
  int qrow0 = (g / NH) * Tq;
  int krow0 = (g / (NH * kdiv)) * Tk;
  int q0 = blockIdx.y * 32;
  int k0 = blockIdx.z * 64;
  __shared__ float Qs[32][68];
  __shared__ float KsT[64][72];   // transposed: [d][k]
  int tid = threadIdx.x;
  {
    int row = tid >> 3, db = (tid & 7) * 8;
    int qr = q0 + row;
    float4 v0 = {0, 0, 0, 0}, v1 = {0, 0, 0, 0};
    if (qr < Tq) {
      const float* p = qp + (size_t)(qrow0 + qr) * Dd + h * DHd + db;
      v0 = *(const float4*)p;
      v1 = *(const float4*)(p + 4);
    }
    *(float4*)&Qs[row][db] = v0;
    *(float4*)&Qs[row][db + 4] = v1;
  }
#pragma unroll
  for (int half = 0; half < 2; half++) {
    int row = (tid >> 3) + half * 32, db = (tid & 7) * 8;
    int kr = k0 + row;
    float4 v0 = {0, 0, 0, 0}, v1 = {0, 0, 0, 0};
    if (kr < Tk) {
      const float* p = kp + (size_t)(krow0 + kr) * ldk + h * DHd + db;
      v0 = *(const float4*)p;
      v1 = *(const float4*)(p + 4);
    }
    KsT[db + 0][row] = v0.x; KsT[db + 1][row] = v0.y;
    KsT[db + 2][row] = v0.z; KsT[db + 3][row] = v0.w;
    KsT[db + 4][row] = v1.x; KsT[db + 5][row] = v1.y;
    KsT[db + 6][row] = v1.z; KsT[db + 7][row] = v1.w;
  }
  __syncthreads();
  int q = tid >> 3, kg = tid & 7;
  float acc[8] = {};
  for (int d = 0; d < DHd; d++) {
    float qv = Qs[q][d];
    float4 k0v = *(const float4*)&KsT[d][kg * 8];
    float4 k1v = *(const float4*)&KsT[d][kg * 8 + 4];
    acc[0] += qv * k0v.x; acc[1] += qv * k0v.y;
    acc[2] += qv * k0v.z; acc[3] += qv * k0v.w;
    acc[4] += qv * k1v.x; acc[5] += qv * k1v.y;
    acc[6] += qv * k1v.z; acc[7] += qv * k1v.w;
  }
  if (q0 + q < Tq) {
    size_t basep = ((size_t)g * Tq + q0 + q) * Tk + k0 + kg * 8;
#pragma unroll
    for (int j = 0; j < 8; j++) Sout[basep + j] = acc[j] * scale;
  }
}

// P@V with fused bf16-split output (Outh/Outl)
__global__ __launch_bounds__(256) void att_pv(const float* __restrict__ P,
                                              const float* __restrict__ vp,
                                              us* __restrict__ Outh,
                                              us* __restrict__ Outl,
                                              int Tq, int Tk, int kdiv, int ldv) {
  int g = blockIdx.x;
  int h = g % NH;
  int qrow0 = (g / NH) * Tq;
  int krow0 = (g / (NH * kdiv)) * Tk;
  int q0 = blockIdx.y * 32;
  __shared__ float Ps[32][68];
  __shared__ float Vs[64][72];
  int tid = threadIdx.x;
  int q = tid >> 3, dg = tid & 7;
  float acc[8] = {};
  for (int k0 = 0; k0 < Tk; k0 += 64) {
    {
      int row = tid >> 3, cb = (tid & 7) * 8;
      int qr = q0 + row;
      float4 v0 = {0, 0, 0, 0}, v1 = {0, 0, 0, 0};
      if (qr < Tq) {
        const float* p = P + ((size_t)g * Tq + qr) * Tk + k0 + cb;
        v0 = *(const float4*)p;
        v1 = *(const float4*)(p + 4);
      }
      *(float4*)&Ps[row][cb] = v0;
      *(float4*)&Ps[row][cb + 4] = v1;
    }
#pragma unroll
    for (int half = 0; half < 2; half++) {
      int row = (tid >> 3) + half * 32, db = (tid & 7) * 8;
      const float* p = vp + (size_t)(krow0 + k0 + row) * ldv + h * DHd + db;
      *(float4*)&Vs[row][db] = *(const float4*)p;
      *(float4*)&Vs[row][db + 4] = *(const float4*)(p + 4);
    }
    __syncthreads();
#pragma unroll 4
    for (int kk4 = 0; kk4 < 16; kk4++) {
      float4 pv = *(const float4*)&Ps[q][kk4 * 4];
      float pe[4] = {pv.x, pv.y, pv.z, pv.w};
#pragma unroll
      for (int e = 0; e < 4; e++) {
        int kk = kk4 * 4 + e;
        float4 v0 = *(const float4*)&Vs[kk][dg * 8];
        float4 v1 = *(const float4*)&Vs[kk][dg * 8 + 4];
        acc[0] += pe[e] * v0.x; acc[1] += pe[e] * v0.y;
        acc[2] += pe[e] * v0.z; acc[3] += pe[e] * v0.w;
        acc[4] += pe[e] * v1.x; acc[5] += pe[e] * v1.y;
        acc[6] += pe[e] * v1.z; acc[7] += pe[e] * v1.w;
      }
    }
    __syncthreads();
  }
  if (q0 + q < Tq) {
    size_t basep = (size_t)(qrow0 + q0 + q) * Dd + h * DHd + dg * 8;
    union { us u[8]; uint4 v; } ph, pl;
#pragma unroll
    for (int j = 0; j < 8; j++) {
      us hb = f2bf(acc[j]);
      ph.u[j] = hb;
      pl.u[j] = f2bf(acc[j] - bf2f(hb));
    }
    *(uint4*)&Outh[basep] = ph.v;
    *(uint4*)&Outl[basep] = pl.v;
  }
}

__global__ __launch_bounds__(256) void softmax_rows(float* __restrict__ X, int len) {
  int row = blockIdx.x;
  float* p = X + (size_t)row * len;
  int tid = threadIdx.x;
  __shared__ float red[4];
  __shared__ float red2[4];
  float lmax = -1e30f;
  for (int j = tid; j < len; j += 256) lmax = fmaxf(lmax, p[j]);
  for (int off = 32; off; off >>= 1) lmax = fmaxf(lmax, __shfl_down(lmax, off));
  if ((tid & 63) == 0) red[tid >> 6] = lmax;
  __syncthreads();
  if (tid == 0) red[0] = fmaxf(fmaxf(red[0], red[1]), fmaxf(red[2], red[3]));
  __syncthreads();
  float m = red[0];
  float lsum = 0.f;
  for (int j = tid; j < len; j += 256) {
    float e = expf(p[j] - m);
    p[j] = e;
    lsum += e;
  }
  for (int off = 32; off; off >>= 1) lsum += __shfl_down(lsum, off);
  if ((tid & 63) == 0) red2[tid >> 6] = lsum;
  __syncthreads();
  if (tid == 0) red2[0] = red2[0] + red2[1] + red2[2] + red2[3];
  __syncthreads();
  float inv = 1.f / red2[0];
  for (int j = tid; j < len; j += 256) p[j] *= inv;
}

// fused head-mean + qv = W @ vatt -> cat slice [0,D)
__global__ __launch_bounds__(256) void qv2_k(const float* __restrict__ S2,
                                             const float* __restrict__ vatt,
                                             us* __restrict__ ch, us* __restrict__ cl) {
  int row = blockIdx.x;
  int b = row / (NST * An);
  int bs = row / An;
  int a = row % An;
  __shared__ float wm[TSn];
  int tid = threadIdx.x;
  if (tid < TSn) {
    float acc = 0.f;
    for (int h = 0; h < NH; h++)
      acc += S2[(((size_t)bs * NH + h) * An + a) * TSn + tid];
    wm[tid] = acc * (1.f / NH);
  }
  __syncthreads();
  for (int j = tid; j < Dd; j += 256) {
    float acc = 0.f;
    for (int k = 0; k < TSn; k++)
      acc += wm[k] * vatt[((size_t)b * TSn + k) * Dd + j];
    size_t o = (size_t)row * DPn + j;
    us hb = f2bf(acc);
    ch[o] = hb;
    cl[o] = f2bf(acc - bf2f(hb));
  }
}

// qa = qf[b] + at[row] -> cat slice [2D,3D)
__global__ void qa_add(const float* __restrict__ qf, const float* __restrict__ at,
                       us* __restrict__ ch, us* __restrict__ cl) {
  int idx = blockIdx.x * 256 + threadIdx.x;
  if (idx >= Bn * NST * An * Dd) return;
  int b = idx / (NST * An * Dd);
  int row = idx / Dd;
  int j = idx % Dd;
  float v = qf[b * Dd + j] + at[idx];
  size_t o = (size_t)row * DPn + 2 * Dd + j;
  us hb = f2bf(v);
  ch[o] = hb;
  cl[o] = f2bf(v - bf2f(hb));
}

// ---------------------------------------------------------------------------
// GRU combine for ALL candidate rows; float4-vectorized; pre-split output.
// Row layout: [0,128): s=0 rows (b,a). [128,Mtot): 128+(((b*7+s-1)*16+a)*16+c).
// ---------------------------------------------------------------------------
__global__ void combine_all(const float* __restrict__ gi,
                            const float* __restrict__ ghALL,
                            const float* __restrict__ gh0,
                            const float* __restrict__ inps,
                            const float* __restrict__ state0,
                            us* __restrict__ Hh, us* __restrict__ Hl) {
  const int D4 = Dd / 4;
  int idx = blockIdx.x * 256 + threadIdx.x;
  if (idx >= Mtot * D4) return;
  int row = idx / D4, j = (idx - row * D4) * 4;
  const float* gp;
  const float* ghp;
  const float* stp;
  if (row < 128) {
    int b = row >> 4, a = row & 15;
    gp = gi + ((size_t)(b * NST) * An + a) * GSn;
    ghp = gh0;
    stp = state0;
  } else {
    int r = row - 128;
    int c = r & 15; r >>= 4;
    int a = r & 15; r >>= 4;
    int sm1 = r % 7, b = r / 7;
    size_t prev = (size_t)(b * NST + sm1) * An + c;
    gp = gi + ((size_t)(b * NST + sm1 + 1) * An + a) * GSn;
    ghp = ghALL + prev * GSn;
    stp = inps + prev * Dd;
  }
  float4 ir4 = *(const float4*)(gp + j);
  float4 iz4 = *(const float4*)(gp + Dd + j);
  float4 in4 = *(const float4*)(gp + 2 * Dd + j);
  float4 hr4 = *(const float4*)(ghp + j);
  float4 hz4 = *(const float4*)(ghp + Dd + j);
  float4 hn4 = *(const float4*)(ghp + 2 * Dd + j);
  float4 st4 = *(const float4*)(stp + j);
  float ir[4] = {ir4.x, ir4.y, ir4.z, ir4.w};
  float iz[4] = {iz4.x, iz4.y, iz4.z, iz4.w};
  float in_[4] = {in4.x, in4.y, in4.z, in4.w};
  float hr[4] = {hr4.x, hr4.y, hr4.z, hr4.w};
  float hz[4] = {hz4.x, hz4.y, hz4.z, hz4.w};
  float hn[4] = {hn4.x, hn4.y, hn4.z, hn4.w};
  float st[4] = {st4.x, st4.y, st4.z, st4.w};
  union { us u[4]; uint2 w; } oh, ol;
#pragma unroll
  for (int t = 0; t < 4; t++) {
    float rg = 1.f / (1.f + expf(-(ir[t] + hr[t])));
    float zg = 1.f / (1.f + expf(-(iz[t] + hz[t])));
    float ng = tanhf(in_[t] + rg * hn[t]);
    float v = (1.f - zg) * ng + zg * st[t];
    us hb = f2bf(v);
    oh.u[t] = hb;
    ol.u[t] = f2bf(v - bf2f(hb));
  }
  *(uint2*)&Hh[(size_t)row * Dd + j] = oh.w;
  *(uint2*)&Hl[(size_t)row * Dd + j] = ol.w;
}

// ---------------------------------------------------------------------------
// pick: walk the argmax chain over logit partials (12 n-tiles).
// ---------------------------------------------------------------------------
__global__ __launch_bounds__(64) void pick_k(const float* __restrict__ Lpart,
                                             const float* __restrict__ b2v,
                                             float* __restrict__ out) {
  int b = blockIdx.x;
  int lane = threadIdx.x;
  int c = 0;
  float b2 = b2v[0];
  for (int s = 0; s < NST; s++) {
    int row;
    if (s == 0) row = b * 16 + (lane & 15);
    else row = 128 + (((b * 7 + (s - 1)) * 16 + (lane & 15)) * 16 + c);
    float v = 0.f;
#pragma unroll
    for (int t = 0; t < 12; t++) v += Lpart[(size_t)t * Mtot + row];
    v += b2;
    if (lane < 16) out[(size_t)(b * NST + s) * An + lane] = v;
    float bv = (lane < 16) ? v : -1e30f;
    int bi = (lane < 16) ? lane : 999;
#pragma unroll
    for (int off = 1; off < 16; off <<= 1) {
      float ov = __shfl_xor(bv, off);
      int oi = __shfl_xor(bi, off);
      if (ov > bv || (ov == bv && oi < bi)) { bv = ov; bi = oi; }
    }
    c = __shfl(bi, 0);
  }
}

// ---------------------------------------------------------------------------
static inline void mm(const us* Ah, const us* Al, int lda, const us* Bh, const us* Bl,
                      const float* bias, float* Cf, int ldc, us* Ch, us* Cl, int ldch,
                      int M, int N, int K, int relu, hipStream_t st) {
  dim3 g(N / 64, M / 64);
  mfma_nt<<<g, 256, 0, st>>>(Ah, Al, lda, Bh, Bl, bias, Cf, ldc, Ch, Cl, ldch, K, relu);
}
static inline void sgemm(const float* A, const float* W, const float* bias, float* C,
                         int M, int N, int K, int lda, int ldc, int relu, hipStream_t st) {
  dim3 g((N + 63) / 64, (M + 63) / 64);
  gemm_s<<<g, 256, 0, st>>>(A, W, bias, C, M, N, K, lda, ldc, relu);
}
static inline void split(const float* x, us* h, us* l, int n, hipStream_t st) {
  int n4 = n >> 2;
  int blocks = (n4 + 255) / 256;
  if (blocks > 2048) blocks = 2048;
  split_k<<<blocks, 256, 0, st>>>(x, h, l, n4);
}

extern "C" void kernel_launch(void* const* d_in, const int* in_sizes, int n_in,
                              void* d_out, int out_size, void* d_ws, size_t ws_size,
                              hipStream_t stream) {
  const float* video     = (const float*)d_in[0];
  const float* script    = (const float*)d_in[1];
  const float* question  = (const float*)d_in[2];
  const float* a_texts   = (const float*)d_in[3];
  const float* a_buttons = (const float*)d_in[4];
  const float* v_w1 = (const float*)d_in[5];
  const float* v_b1 = (const float*)d_in[6];
  const float* v_w2 = (const float*)d_in[7];
  const float* v_b2 = (const float*)d_in[8];
  const float* t_w1 = (const float*)d_in[9];
  const float* t_b1 = (const float*)d_in[10];
  const float* t_w2 = (const float*)d_in[11];
  const float* t_b2 = (const float*)d_in[12];
  const float* pre_w1 = (const float*)d_in[13];
  const float* pre_b1 = (const float*)d_in[14];
  const float* pre_w2 = (const float*)d_in[15];
  const float* pre_b2 = (const float*)d_in[16];
  const float* s2v_win  = (const float*)d_in[17];
  const float* s2v_bin  = (const float*)d_in[18];
  const float* s2v_wout = (const float*)d_in[19];
  const float* s2v_bout = (const float*)d_in[20];
  const float* qa_win  = (const float*)d_in[21];
  const float* qa_bin  = (const float*)d_in[22];
  const float* qa_wout = (const float*)d_in[23];
  const float* qa_bout = (const float*)d_in[24];
  const float* gru_wih = (const float*)d_in[25];
  const float* gru_whh = (const float*)d_in[26];
  const float* gru_bih = (const float*)d_in[27];
  const float* gru_bhh = (const float*)d_in[28];
  const float* proj_w1 = (const float*)d_in[29];
  const float* proj_b1 = (const float*)d_in[30];
  const float* proj_w2 = (const float*)d_in[31];
  const float* proj_b2 = (const float*)d_in[32];
  const float* state0  = (const float*)d_in[33];
  (void)in_sizes; (void)n_in; (void)out_size; (void)ws_size;

  constexpr int W589  = 768 * 768;
  constexpr int W1769 = 2304 * 768;
  constexpr int W9437 = 3072 * 3072;
  constexpr int W2359 = 768 * 3072;
  constexpr int SMe   = 1024 * 768;
  constexpr int BIGe  = 4096 * 768;

  char* base = (char*)d_ws;
  char* RW1 = base;                   // 9,437,184 : phase-A weights -> ghALL
  char* RW2 = RW1 + 9437184;          // 9,437,184 : s2v/qa/pre_w2 weights -> gi
  char* R1  = RW2 + 9437184;          // 28,311,552
  char* R2  = R1 + 28311552;          // 12,582,912
  char* X   = R2 + 12582912;          // 25,165,824
  char* P   = X + 25165824;           // ~20 MB persistents

  us* vw1h = (us*)RW1;        us* vw1l = vw1h + W589;
  us* vw2h = vw1l + W589;     us* vw2l = vw2h + W589;
  us* tw1h = vw2l + W589;     us* tw1l = tw1h + W589;
  us* tw2h = tw1l + W589;     us* tw2l = tw2h + W589;
  float* ghALL = (float*)RW1;           // after phase-A weights dead
  us* s2vwh = (us*)RW2;       us* s2vwl = s2vwh + W1769;
  us* s2voh = s2vwl + W1769;  us* s2vol = s2voh + W589;
  us* qawh  = (us*)RW2;       us* qawl  = qawh + W1769;
  us* qaoh  = qawl + W1769;   us* qaol  = qaoh + W589;
  us* pw2h  = (us*)RW2;       us* pw2l  = pw2h + W2359;
  float* gi = (float*)RW2;              // after pw2 dead
  us* vidh = (us*)R1;         us* vidl = vidh + BIGe;
  us* hidh = vidl + BIGe;     us* hidl = hidh + BIGe;
  us* scrh = (us*)R1;         us* scrl = scrh + SMe;
  float* kvproj = (float*)R1;
  float* qproj  = kvproj + (size_t)4096 * 1536;
  float* kv2 = (float*)R1;
  float* qp2 = (float*)(R1 + 6291456);
  float* S2  = (float*)(R1 + 9437184);
  us* abhh = (us*)(R1 + 15728640); us* abhl = abhh + SMe;
  us* pw1h = (us*)R1;         us* pw1l = pw1h + W9437;
  us* gwihh = (us*)R1;        us* gwihl = gwihh + W1769;
  us* pjw1h = (us*)(R1 + 7077888);  us* pjw1l = pjw1h + W589;
  us* gwhhh = (us*)(R1 + 9437184);  us* gwhhl = gwhhh + W1769;
  us* vh = (us*)R2;           us* vl = vh + BIGe;
  us* aoh = (us*)(R2 + 3145728); us* aol = aoh + SMe;
  // candidate matrix (pre-split): spans R2+X and the dead prefix of P
  us* Hh = (us*)R2;           us* Hl = Hh + (size_t)Mtot * Dd;
  float* S1 = (float*)X;
  us* cath = (us*)X;          us* catl = cath + (size_t)1024 * DPn;
  us* prehh = (us*)(X + 12582912); us* prehl = prehh + (size_t)1024 * DPn;
  us* abinh = (us*)P;         us* abinl = abinh + SMe;
  us* sch   = (us*)(P + 3145728); us* scl = sch + SMe;
  float* at_f   = (float*)(P + 6291456);
  float* vatt   = (float*)(P + 9437184);
  float* inps_f = (float*)(P + 12582912);
  us* inpsh = (us*)(P + 15728640); us* inpsl = inpsh + SMe;
  float* qf    = (float*)(P + 18874368);
  float* qhid  = (float*)(P + 18898944);
  float* gh0   = (float*)(P + 18923520);
  float* Lpart = (float*)(P + 18932736);   // 12 x 14464 f32

  // ---- phase A ----
  split4_k<<<dim3(1024, 4), 256, 0, stream>>>(v_w1, vw1h, vw1l, W589,
                                              v_w2, vw2h, vw2l, W589,
                                              t_w1, tw1h, tw1l, W589,
                                              t_w2, tw2h, tw2l, W589);
  split(video, vidh, vidl, BIGe, stream);
  mm(vidh, vidl, Dd, vw1h, vw1l, v_b1, nullptr, 0, hidh, hidl, Dd, 4096, Dd, Dd, 1, stream);
  mm(hidh, hidl, Dd, vw2h, vw2l, v_b2, nullptr, 0, vh, vl, Dd, 4096, Dd, Dd, 0, stream);
  split(script, scrh, scrl, SMe, stream);
  mm(scrh, scrl, Dd, tw1h, tw1l, t_b1, nullptr, 0, hidh, hidl, Dd, 1024, Dd, Dd, 1, stream);
  mm(hidh, hidl, Dd, tw2h, tw2l, t_b2, nullptr, 0, sch, scl, Dd, 1024, Dd, Dd, 0, stream);
  sgemm(question, t_w1, t_b1, qhid, Bn, Dd, Dd, Dd, Dd, 1, stream);
  sgemm(qhid, t_w2, t_b2, qf, Bn, Dd, Dd, Dd, Dd, 0, stream);
  split(a_texts, scrh, scrl, SMe, stream);
  mm(scrh, scrl, Dd, tw1h, tw1l, t_b1, nullptr, 0, hidh, hidl, Dd, 1024, Dd, Dd, 1, stream);
  mm(hidh, hidl, Dd, tw2h, tw2l, t_b2, at_f, Dd, nullptr, nullptr, 0, 1024, Dd, Dd, 0, stream);
  split(a_buttons, abinh, abinl, SMe, stream);

  // ---- s2v attention (K/V merged: N=1536) ----
  split4_k<<<dim3(1024, 4), 256, 0, stream>>>(s2v_win, s2vwh, s2vwl, W1769,
                                              s2v_wout, s2voh, s2vol, W589,
                                              nullptr, nullptr, nullptr, 0,
                                              nullptr, nullptr, nullptr, 0);
  mm(vh, vl, Dd, s2vwh + (size_t)Dd * Dd, s2vwl + (size_t)Dd * Dd, s2v_bin + Dd,
     kvproj, 1536, nullptr, nullptr, 0, 4096, 1536, Dd, 0, stream);
  mm(sch, scl, Dd, s2vwh, s2vwl, s2v_bin, qproj, Dd, nullptr, nullptr, 0, 1024, Dd, Dd, 0, stream);
  att_qk<<<dim3(Bn * NH, TSn / 32, TVn / 64), 256, 0, stream>>>(qproj, kvproj, S1,
                                                                TSn, TVn, 1, 1536, 0.125f);
  softmax_rows<<<Bn * NH * TSn, 256, 0, stream>>>(S1, TVn);
  att_pv<<<dim3(Bn * NH, TSn / 32), 256, 0, stream>>>(S1, kvproj + Dd, aoh, aol,
                                                      TSn, TVn, 1, 1536);
  mm(aoh, aol, Dd, s2voh, s2vol, s2v_bout, vatt, Dd, nullptr, nullptr, 0, 1024, Dd, Dd, 0, stream);

  // ---- phase B: ab MLP, qa attention ----
  mm(abinh, abinl, Dd, vw1h, vw1l, v_b1, nullptr, 0, abhh, abhl, Dd, 1024, Dd, Dd, 1, stream);
  mm(abhh, abhl, Dd, vw2h, vw2l, v_b2, nullptr, 0, cath + 3 * Dd, catl + 3 * Dd, DPn,
     1024, Dd, Dd, 0, stream);
  qa_add<<<(1024 * Dd + 255) / 256, 256, 0, stream>>>(qf, at_f, cath, catl);
  split4_k<<<dim3(1024, 4), 256, 0, stream>>>(qa_win, qawh, qawl, W1769,
                                              qa_wout, qaoh, qaol, W589,
                                              nullptr, nullptr, nullptr, 0,
                                              nullptr, nullptr, nullptr, 0);
  mm(sch, scl, Dd, qawh + (size_t)Dd * Dd, qawl + (size_t)Dd * Dd, qa_bin + Dd,
     kv2, 1536, nullptr, nullptr, 0, 1024, 1536, Dd, 0, stream);
  mm(cath + 2 * Dd, catl + 2 * Dd, DPn, qawh, qawl, qa_bin, qp2, Dd, nullptr, nullptr, 0,
     1024, Dd, Dd, 0, stream);
  att_qk<<<dim3(Bn * NST * NH, 1, TSn / 64), 256, 0, stream>>>(qp2, kv2, S2,
                                                               An, TSn, NST, 1536, 0.125f);
  softmax_rows<<<Bn * NST * NH * An, 256, 0, stream>>>(S2, TSn);
  att_pv<<<dim3(Bn * NST * NH, 1), 256, 0, stream>>>(S2, kv2 + Dd, aoh, aol,
                                                     An, TSn, NST, 1536);
  mm(aoh, aol, Dd, qaoh, qaol, qa_bout, nullptr, 0, cath + Dd, catl + Dd, DPn,
     1024, Dd, Dd, 0, stream);
  qv2_k<<<1024, 256, 0, stream>>>(S2, vatt, cath, catl);

  // ---- pre-MLP + GRU gates ----
  split(pre_w1, pw1h, pw1l, W9437, stream);
  mm(cath, catl, DPn, pw1h, pw1l, pre_b1, nullptr, 0, prehh, prehl, DPn,
     1024, DPn, DPn, 1, stream);
  split4_k<<<dim3(1024, 4), 256, 0, stream>>>(pre_w2, pw2h, pw2l, W2359,
                                              gru_wih, gwihh, gwihl, W1769,
                                              gru_whh, gwhhh, gwhhl, W1769,
                                              proj_w1, pjw1h, pjw1l, W589);
  mm(prehh, prehl, DPn, pw2h, pw2l, pre_b2, inps_f, Dd, inpsh, inpsl, Dd,
     1024, Dd, DPn, 0, stream);
  mm(inpsh, inpsl, Dd, gwihh, gwihl, gru_bih, gi, GSn, nullptr, nullptr, 0,
     1024, GSn, Dd, 0, stream);
  mm(inpsh, inpsl, Dd, gwhhh, gwhhl, gru_bhh, ghALL, GSn, nullptr, nullptr, 0,
     1024, GSn, Dd, 0, stream);
  sgemm(state0, gru_whh, gru_bhh, gh0, 1, GSn, Dd, Dd, GSn, 0, stream);

  // ---- candidate enumeration + logits + argmax chain ----
  combine_all<<<(Mtot * (Dd / 4) + 255) / 256, 256, 0, stream>>>(gi, ghALL, gh0, inps_f,
                                                                 state0, Hh, Hl);
  mfma_logit<<<dim3(Dd / 64, Mtot / 64), 256, 0, stream>>>(Hh, Hl, pjw1h, pjw1l,
                                                           proj_b1, proj_w2, Lpart);
  pick_k<<<Bn, 64, 0, stream>>>(Lpart, proj_b2, (float*)d_out);
}

// Round 11
// 1192.699 us; speedup vs baseline: 1.8442x; 1.7033x over previous
//
#include <hip/hip_runtime.h>
#include <hip/hip_bf16.h>
#include <math.h>

constexpr int Dd  = 768;
constexpr int NH  = 12;
constexpr int DHd = 64;
constexpr int Bn  = 8;
constexpr int TVn = 512;
constexpr int TSn = 128;
constexpr int NST = 8;
constexpr int An  = 16;
constexpr int DPn = 3072;
constexpr int GSn = 2304;
constexpr int Mtot = 14464;   // 128 (s=0) + 8*7*16*16 candidate rows; 226*64

typedef unsigned short us;
using short8   = __attribute__((ext_vector_type(8))) short;
using floatx16 = __attribute__((ext_vector_type(16))) float;

__device__ inline us f2bf(float x) {
  union { float f; unsigned u; } a; a.f = x;
  return (us)((a.u + 0x7fffu + ((a.u >> 16) & 1u)) >> 16);
}
__device__ inline float bf2f(us h) {
  union { unsigned u; float f; } a; a.u = ((unsigned)h) << 16;
  return a.f;
}

// ---------------------------------------------------------------------------
// splits (float4-vectorized)
// ---------------------------------------------------------------------------
__global__ void split_k(const float* __restrict__ x, us* __restrict__ h,
                        us* __restrict__ l, int n4) {
  for (int i = blockIdx.x * 256 + threadIdx.x; i < n4; i += gridDim.x * 256) {
    float4 v = ((const float4*)x)[i];
    float vv[4] = {v.x, v.y, v.z, v.w};
    union { us u[4]; uint2 w; } hh, ll;
#pragma unroll
    for (int t = 0; t < 4; t++) {
      us hb = f2bf(vv[t]);
      hh.u[t] = hb;
      ll.u[t] = f2bf(vv[t] - bf2f(hb));
    }
    ((uint2*)h)[i] = hh.w;
    ((uint2*)l)[i] = ll.w;
  }
}

__global__ void split4_k(const float* s0, us* h0, us* l0, int n0,
                         const float* s1, us* h1, us* l1, int n1,
                         const float* s2, us* h2, us* l2, int n2,
                         const float* s3, us* h3, us* l3, int n3) {
  const float* s; us* h; us* l; int n;
  switch (blockIdx.y) {
    case 0: s = s0; h = h0; l = l0; n = n0; break;
    case 1: s = s1; h = h1; l = l1; n = n1; break;
    case 2: s = s2; h = h2; l = l2; n = n2; break;
    default: s = s3; h = h3; l = l3; n = n3; break;
  }
  int n4 = n >> 2;
  for (int i = blockIdx.x * 256 + threadIdx.x; i < n4; i += gridDim.x * 256) {
    float4 v = ((const float4*)s)[i];
    float vv[4] = {v.x, v.y, v.z, v.w};
    union { us u[4]; uint2 w; } hh, ll;
#pragma unroll
    for (int t = 0; t < 4; t++) {
      us hb = f2bf(vv[t]);
      hh.u[t] = hb;
      ll.u[t] = f2bf(vv[t] - bf2f(hb));
    }
    ((uint2*)h)[i] = hh.w;
    ((uint2*)l)[i] = ll.w;
  }
}

__device__ inline short8 lds8(const us* p) {
  const uint2* q = (const uint2*)p;
  uint2 a = q[0], b = q[1];
  union { unsigned u[4]; short8 v; } t;
  t.u[0] = a.x; t.u[1] = a.y; t.u[2] = b.x; t.u[3] = b.y;
  return t.v;
}

// ---------------------------------------------------------------------------
// bf16x3 MFMA NT GEMM — R5 structure (empirically best: 109us @ pre_w1).
// 64x64 tile, 4 waves, 3 acc chains, dbuf LDS (runtime p), scalar prefetch
// regs, 1 barrier/iter, distance-1 prefetch. Dual-bias epilogue for merged
// GEMMs: bias[n] if n<nsplit else bias2[n-nsplit].
// ---------------------------------------------------------------------------
__global__ __launch_bounds__(256) void mfma_nt(
    const us* __restrict__ Ah, const us* __restrict__ Al, int lda,
    const us* __restrict__ Bh, const us* __restrict__ Bl,
    const float* __restrict__ bias, const float* __restrict__ bias2, int nsplit,
    float* __restrict__ Cf, int ldc,
    us* __restrict__ Ch, us* __restrict__ Cl, int ldch,
    int K, int relu) {
  __shared__ us Ash[2][64][36], Asl[2][64][36], Bsh[2][64][36], Bsl[2][64][36];
  const int tid = threadIdx.x;
  const int bm = blockIdx.y * 64, bn = blockIdx.x * 64;
  const int wave = tid >> 6, lane = tid & 63;
  const int mh = (wave & 1) * 32, nh = (wave >> 1) * 32;
  const int l31 = lane & 31, hi5 = lane >> 5;
  const int srow = tid >> 2, skc = (tid & 3) * 8;
  const us* pAh = Ah + (size_t)(bm + srow) * lda + skc;
  const us* pAl = Al + (size_t)(bm + srow) * lda + skc;
  const us* pBh = Bh + (size_t)(bn + srow) * K + skc;
  const us* pBl = Bl + (size_t)(bn + srow) * K + skc;

  floatx16 acc_hh, acc_hl, acc_lh;
#pragma unroll
  for (int i = 0; i < 16; i++) { acc_hh[i] = 0.f; acc_hl[i] = 0.f; acc_lh[i] = 0.f; }

  uint4 a_h = *(const uint4*)pAh;
  uint4 a_l = *(const uint4*)pAl;
  uint4 b_h = *(const uint4*)pBh;
  uint4 b_l = *(const uint4*)pBl;
  const int iters = K >> 5;
  int p = 0;
  for (int it = 0; it < iters; ++it) {
    *(uint2*)&Ash[p][srow][skc]     = make_uint2(a_h.x, a_h.y);
    *(uint2*)&Ash[p][srow][skc + 4] = make_uint2(a_h.z, a_h.w);
    *(uint2*)&Asl[p][srow][skc]     = make_uint2(a_l.x, a_l.y);
    *(uint2*)&Asl[p][srow][skc + 4] = make_uint2(a_l.z, a_l.w);
    *(uint2*)&Bsh[p][srow][skc]     = make_uint2(b_h.x, b_h.y);
    *(uint2*)&Bsh[p][srow][skc + 4] = make_uint2(b_h.z, b_h.w);
    *(uint2*)&Bsl[p][srow][skc]     = make_uint2(b_l.x, b_l.y);
    *(uint2*)&Bsl[p][srow][skc + 4] = make_uint2(b_l.z, b_l.w);
    __syncthreads();
    int knext = (it + 1 < iters) ? (it + 1) * 32 : 0;
    a_h = *(const uint4*)(pAh + knext);
    a_l = *(const uint4*)(pAl + knext);
    b_h = *(const uint4*)(pBh + knext);
    b_l = *(const uint4*)(pBl + knext);
#pragma unroll
    for (int ks = 0; ks < 32; ks += 16) {
      short8 fa_h = lds8(&Ash[p][mh + l31][ks + hi5 * 8]);
      short8 fa_l = lds8(&Asl[p][mh + l31][ks + hi5 * 8]);
      short8 fb_h = lds8(&Bsh[p][nh + l31][ks + hi5 * 8]);
      short8 fb_l = lds8(&Bsl[p][nh + l31][ks + hi5 * 8]);
      acc_hh = __builtin_amdgcn_mfma_f32_32x32x16_bf16(fa_h, fb_h, acc_hh, 0, 0, 0);
      acc_hl = __builtin_amdgcn_mfma_f32_32x32x16_bf16(fa_h, fb_l, acc_hl, 0, 0, 0);
      acc_lh = __builtin_amdgcn_mfma_f32_32x32x16_bf16(fa_l, fb_h, acc_lh, 0, 0, 0);
    }
    p ^= 1;
  }
  int n = bn + nh + l31;
  float bv = (n < nsplit) ? bias[n] : bias2[n - nsplit];
#pragma unroll
  for (int r = 0; r < 16; r++) {
    int m = bm + mh + (r & 3) + 8 * (r >> 2) + 4 * hi5;
    float v = acc_hh[r] + acc_hl[r] + acc_lh[r] + bv;
    if (relu) v = fmaxf(v, 0.f);
    if (Cf) Cf[(size_t)m * ldc + n] = v;
    if (Ch) {
      us hb = f2bf(v);
      Ch[(size_t)m * ldch + n] = hb;
      Cl[(size_t)m * ldch + n] = f2bf(v - bf2f(hb));
    }
  }
}

// ---------------------------------------------------------------------------
// logit GEMM: R5 loop, pre-split A (Hh,Hl) [Mtot x 768], B = proj_w1 split.
// Epilogue: relu(acc+b1[n])*w2[n], reduce over 64-col n-tile ->
// Lpart[ntile][m]. Grid (12, Mtot/64).
// ---------------------------------------------------------------------------
__global__ __launch_bounds__(256) void mfma_logit(
    const us* __restrict__ Ah, const us* __restrict__ Al,
    const us* __restrict__ Bh, const us* __restrict__ Bl,
    const float* __restrict__ bias1, const float* __restrict__ w2,
    float* __restrict__ Lpart) {
  __shared__ us Ash[2][64][36], Asl[2][64][36], Bsh[2][64][36], Bsl[2][64][36];
  __shared__ float lpart[64];
  const int K = Dd;
  const int tid = threadIdx.x;
  const int bm = blockIdx.y * 64, bn = blockIdx.x * 64;
  const int wave = tid >> 6, lane = tid & 63;
  const int mh = (wave & 1) * 32, nh = (wave >> 1) * 32;
  const int l31 = lane & 31, hi5 = lane >> 5;
  const int srow = tid >> 2, skc = (tid & 3) * 8;
  const us* pAh = Ah + (size_t)(bm + srow) * K + skc;
  const us* pAl = Al + (size_t)(bm + srow) * K + skc;
  const us* pBh = Bh + (size_t)(bn + srow) * K + skc;
  const us* pBl = Bl + (size_t)(bn + srow) * K + skc;
  if (tid < 64) lpart[tid] = 0.f;

  floatx16 acc_hh, acc_hl, acc_lh;
#pragma unroll
  for (int i = 0; i < 16; i++) { acc_hh[i] = 0.f; acc_hl[i] = 0.f; acc_lh[i] = 0.f; }

  uint4 a_h = *(const uint4*)pAh;
  uint4 a_l = *(const uint4*)pAl;
  uint4 b_h = *(const uint4*)pBh;
  uint4 b_l = *(const uint4*)pBl;
  const int iters = K >> 5;
  int p = 0;
  for (int it = 0; it < iters; ++it) {
    *(uint2*)&Ash[p][srow][skc]     = make_uint2(a_h.x, a_h.y);
    *(uint2*)&Ash[p][srow][skc + 4] = make_uint2(a_h.z, a_h.w);
    *(uint2*)&Asl[p][srow][skc]     = make_uint2(a_l.x, a_l.y);
    *(uint2*)&Asl[p][srow][skc + 4] = make_uint2(a_l.z, a_l.w);
    *(uint2*)&Bsh[p][srow][skc]     = make_uint2(b_h.x, b_h.y);
    *(uint2*)&Bsh[p][srow][skc + 4] = make_uint2(b_h.z, b_h.w);
    *(uint2*)&Bsl[p][srow][skc]     = make_uint2(b_l.x, b_l.y);
    *(uint2*)&Bsl[p][srow][skc + 4] = make_uint2(b_l.z, b_l.w);
    __syncthreads();
    int knext = (it + 1 < iters) ? (it + 1) * 32 : 0;
    a_h = *(const uint4*)(pAh + knext);
    a_l = *(const uint4*)(pAl + knext);
    b_h = *(const uint4*)(pBh + knext);
    b_l = *(const uint4*)(pBl + knext);
#pragma unroll
    for (int ks = 0; ks < 32; ks += 16) {
      short8 fa_h = lds8(&Ash[p][mh + l31][ks + hi5 * 8]);
      short8 fa_l = lds8(&Asl[p][mh + l31][ks + hi5 * 8]);
      short8 fb_h = lds8(&Bsh[p][nh + l31][ks + hi5 * 8]);
      short8 fb_l = lds8(&Bsl[p][nh + l31][ks + hi5 * 8]);
      acc_hh = __builtin_amdgcn_mfma_f32_32x32x16_bf16(fa_h, fb_h, acc_hh, 0, 0, 0);
      acc_hl = __builtin_amdgcn_mfma_f32_32x32x16_bf16(fa_h, fb_l, acc_hl, 0, 0, 0);
      acc_lh = __builtin_amdgcn_mfma_f32_32x32x16_bf16(fa_l, fb_h, acc_lh, 0, 0, 0);
    }
    p ^= 1;
  }
  int n = bn + nh + l31;
  float bn1 = bias1[n], wn = w2[n];
#pragma unroll
  for (int r = 0; r < 16; r++) {
    int mloc = mh + (r & 3) + 8 * (r >> 2) + 4 * hi5;
    float v = acc_hh[r] + acc_hl[r] + acc_lh[r] + bn1;
    v = fmaxf(v, 0.f) * wn;
    v += __shfl_xor(v, 1);
    v += __shfl_xor(v, 2);
    v += __shfl_xor(v, 4);
    v += __shfl_xor(v, 8);
    v += __shfl_xor(v, 16);
    if (l31 == 0) atomicAdd(&lpart[mloc], v);
  }
  __syncthreads();
  if (tid < 64) Lpart[(size_t)blockIdx.x * Mtot + bm + tid] = lpart[tid];
}

// ---------------------------------------------------------------------------
// scalar f32 NT GEMM (tiny M: question, gh0)
// ---------------------------------------------------------------------------
__global__ __launch_bounds__(256) void gemm_s(const float* __restrict__ A,
                                              const float* __restrict__ Bw,
                                              const float* __restrict__ bias,
                                              float* __restrict__ C,
                                              int M, int N, int K,
                                              int lda, int ldc, int relu) {
  __shared__ float As[16][65];
  __shared__ float Bs[16][65];
  int bm = blockIdx.y * 64, bn = blockIdx.x * 64;
  int tid = threadIdx.x;
  int tx = tid & 15, ty = tid >> 4;
  float acc[4][4] = {};
  for (int k0 = 0; k0 < K; k0 += 16) {
#pragma unroll
    for (int i = 0; i < 4; i++) {
      int l = tid * 4 + i;
      int row = l >> 4, kk = l & 15;
      float v = 0.f;
      if (bm + row < M) v = A[(size_t)(bm + row) * lda + k0 + kk];
      As[kk][row] = v;
    }
#pragma unroll
    for (int i = 0; i < 4; i++) {
      int l = tid * 4 + i;
      int row = l >> 4, kk = l & 15;
      float v = 0.f;
      if (bn + row < N) v = Bw[(size_t)(bn + row) * K + k0 + kk];
      Bs[kk][row] = v;
    }
    __syncthreads();
#pragma unroll
    for (int kk = 0; kk < 16; kk++) {
      float a4[4], b4[4];
#pragma unroll
      for (int i = 0; i < 4; i++) a4[i] = As[kk][ty * 4 + i];
#pragma unroll
      for (int j = 0; j < 4; j++) b4[j] = Bs[kk][tx * 4 + j];
#pragma unroll
      for (int i = 0; i < 4; i++)
#pragma unroll
        for (int j = 0; j < 4; j++) acc[i][j] += a4[i] * b4[j];
    }
    __syncthreads();
  }
#pragma unroll
  for (int i = 0; i < 4; i++) {
    int m = bm + ty * 4 + i;
    if (m >= M) continue;
#pragma unroll
    for (int j = 0; j < 4; j++) {
      int n = bn + tx * 4 + j;
      if (n >= N) continue;
      float v = acc[i][j] + bias[n];
      if (relu) v = fmaxf(v, 0.f);
      C[(size_t)m * ldc + n] = v;
    }
  }
}

// ---------------------------------------------------------------------------
// attention (f32), float4-vectorized LDS
// ---------------------------------------------------------------------------
__global__ __launch_bounds__(256) void att_qk(const float* __restrict__ qp,
                                              const float* __restrict__ kp,
                                              float* __restrict__ Sout,
                                              int Tq, int Tk, int kdiv, int ldk,
                                              float scale) {
  int g = blockIdx.x;
  int h = g % NH;
  int qrow0 = (g / NH) * Tq;
  int krow0 = (g / (NH * kdiv)) * Tk;
  int q0 = blockIdx.y * 32;
  int k0 = blockIdx.z * 64;
  __shared__ float Qs[32][68];
  __shared__ float KsT[64][72];   // transposed: [d][k]
  int tid = threadIdx.x;
  {
    int row = tid >> 3, db = (tid & 7) * 8;
    int qr = q0 + row;
    float4 v0 = {0, 0, 0, 0}, v1 = {0, 0, 0, 0};
    if (qr < Tq) {
      const float* p = qp + (size_t)(qrow0 + qr) * Dd + h * DHd + db;
      v0 = *(const float4*)p;
      v1 = *(const float4*)(p + 4);
    }
    *(float4*)&Qs[row][db] = v0;
    *(float4*)&Qs[row][db + 4] = v1;
  }
#pragma unroll
  for (int half = 0; half < 2; half++) {
    int row = (tid >> 3) + half * 32, db = (tid & 7) * 8;
    int kr = k0 + row;
    float4 v0 = {0, 0, 0, 0}, v1 = {0, 0, 0, 0};
    if (kr < Tk) {
      const float* p = kp + (size_t)(krow0 + kr) * ldk + h * DHd + db;
      v0 = *(const float4*)p;
      v1 = *(const float4*)(p + 4);
    }
    KsT[db + 0][row] = v0.x; KsT[db + 1][row] = v0.y;
    KsT[db + 2][row] = v0.z; KsT[db + 3][row] = v0.w;
    KsT[db + 4][row] = v1.x; KsT[db + 5][row] = v1.y;
    KsT[db + 6][row] = v1.z; KsT[db + 7][row] = v1.w;
  }
  __syncthreads();
  int q = tid >> 3, kg = tid & 7;
  float acc[8] = {};
  for (int d = 0; d < DHd; d++) {
    float qv = Qs[q][d];
    float4 k0v = *(const float4*)&KsT[d][kg * 8];
    float4 k1v = *(const float4*)&KsT[d][kg * 8 + 4];
    acc[0] += qv * k0v.x; acc[1] += qv * k0v.y;
    acc[2] += qv * k0v.z; acc[3] += qv * k0v.w;
    acc[4] += qv * k1v.x; acc[5] += qv * k1v.y;
    acc[6] += qv * k1v.z; acc[7] += qv * k1v.w;
  }
  if (q0 + q < Tq) {
    size_t basep = ((size_t)g * Tq + q0 + q) * Tk + k0 + kg * 8;
#pragma unroll
    for (int j = 0; j < 8; j++) Sout[basep + j] = acc[j] * scale;
  }
}

// P@V with fused bf16-split output (Outh/Outl)
__global__ __launch_bounds__(256) void att_pv(const float* __restrict__ P,
                                              const float* __restrict__ vp,
                                              us* __restrict__ Outh,
                                              us* __restrict__ Outl,
                                              int Tq, int Tk, int kdiv, int ldv) {
  int g = blockIdx.x;
  int h = g % NH;
  int qrow0 = (g / NH) * Tq;
  int krow0 = (g / (NH * kdiv)) * Tk;
  int q0 = blockIdx.y * 32;
  __shared__ float Ps[32][68];
  __shared__ float Vs[64][72];
  int tid = threadIdx.x;
  int q = tid >> 3, dg = tid & 7;
  float acc[8] = {};
  for (int k0 = 0; k0 < Tk; k0 += 64) {
    {
      int row = tid >> 3, cb = (tid & 7) * 8;
      int qr = q0 + row;
      float4 v0 = {0, 0, 0, 0}, v1 = {0, 0, 0, 0};
      if (qr < Tq) {
        const float* p = P + ((size_t)g * Tq + qr) * Tk + k0 + cb;
        v0 = *(const float4*)p;
        v1 = *(const float4*)(p + 4);
      }
      *(float4*)&Ps[row][cb] = v0;
      *(float4*)&Ps[row][cb + 4] = v1;
    }
#pragma unroll
    for (int half = 0; half < 2; half++) {
      int row = (tid >> 3) + half * 32, db = (tid & 7) * 8;
      const float* p = vp + (size_t)(krow0 + k0 + row) * ldv + h * DHd + db;
      *(float4*)&Vs[row][db] = *(const float4*)p;
      *(float4*)&Vs[row][db + 4] = *(const float4*)(p + 4);
    }
    __syncthreads();
#pragma unroll 4
    for (int kk4 = 0; kk4 < 16; kk4++) {
      float4 pv = *(const float4*)&Ps[q][kk4 * 4];
      float pe[4] = {pv.x, pv.y, pv.z, pv.w};
#pragma unroll
      for (int e = 0; e < 4; e++) {
        int kk = kk4 * 4 + e;
        float4 v0 = *(const float4*)&Vs[kk][dg * 8];
        float4 v1 = *(const float4*)&Vs[kk][dg * 8 + 4];
        acc[0] += pe[e] * v0.x; acc[1] += pe[e] * v0.y;
        acc[2] += pe[e] * v0.z; acc[3] += pe[e] * v0.w;
        acc[4] += pe[e] * v1.x; acc[5] += pe[e] * v1.y;
        acc[6] += pe[e] * v1.z; acc[7] += pe[e] * v1.w;
      }
    }
    __syncthreads();
  }
  if (q0 + q < Tq) {
    size_t basep = (size_t)(qrow0 + q0 + q) * Dd + h * DHd + dg * 8;
    union { us u[8]; uint4 v; } ph, pl;
#pragma unroll
    for (int j = 0; j < 8; j++) {
      us hb = f2bf(acc[j]);
      ph.u[j] = hb;
      pl.u[j] = f2bf(acc[j] - bf2f(hb));
    }
    *(uint4*)&Outh[basep] = ph.v;
    *(uint4*)&Outl[basep] = pl.v;
  }
}

__global__ __launch_bounds__(256) void softmax_rows(float* __restrict__ X, int len) {
  int row = blockIdx.x;
  float* p = X + (size_t)row * len;
  int tid = threadIdx.x;
  __shared__ float red[4];
  __shared__ float red2[4];
  float lmax = -1e30f;
  for (int j = tid; j < len; j += 256) lmax = fmaxf(lmax, p[j]);
  for (int off = 32; off; off >>= 1) lmax = fmaxf(lmax, __shfl_down(lmax, off));
  if ((tid & 63) == 0) red[tid >> 6] = lmax;
  __syncthreads();
  if (tid == 0) red[0] = fmaxf(fmaxf(red[0], red[1]), fmaxf(red[2], red[3]));
  __syncthreads();
  float m = red[0];
  float lsum = 0.f;
  for (int j = tid; j < len; j += 256) {
    float e = expf(p[j] - m);
    p[j] = e;
    lsum += e;
  }
  for (int off = 32; off; off >>= 1) lsum += __shfl_down(lsum, off);
  if ((tid & 63) == 0) red2[tid >> 6] = lsum;
  __syncthreads();
  if (tid == 0) red2[0] = red2[0] + red2[1] + red2[2] + red2[3];
  __syncthreads();
  float inv = 1.f / red2[0];
  for (int j = tid; j < len; j += 256) p[j] *= inv;
}

// fused head-mean + qv = W @ vatt -> cat slice [0,D)
__global__ __launch_bounds__(256) void qv2_k(const float* __restrict__ S2,
                                             const float* __restrict__ vatt,
                                             us* __restrict__ ch, us* __restrict__ cl) {
  int row = blockIdx.x;
  int b = row / (NST * An);
  int bs = row / An;
  int a = row % An;
  __shared__ float wm[TSn];
  int tid = threadIdx.x;
  if (tid < TSn) {
    float acc = 0.f;
    for (int h = 0; h < NH; h++)
      acc += S2[(((size_t)bs * NH + h) * An + a) * TSn + tid];
    wm[tid] = acc * (1.f / NH);
  }
  __syncthreads();
  for (int j = tid; j < Dd; j += 256) {
    float acc = 0.f;
    for (int k = 0; k < TSn; k++)
      acc += wm[k] * vatt[((size_t)b * TSn + k) * Dd + j];
    size_t o = (size_t)row * DPn + j;
    us hb = f2bf(acc);
    ch[o] = hb;
    cl[o] = f2bf(acc - bf2f(hb));
  }
}

// qa = qf[b] + at[row] -> cat slice [2D,3D)
__global__ void qa_add(const float* __restrict__ qf, const float* __restrict__ at,
                       us* __restrict__ ch, us* __restrict__ cl) {
  int idx = blockIdx.x * 256 + threadIdx.x;
  if (idx >= Bn * NST * An * Dd) return;
  int b = idx / (NST * An * Dd);
  int row = idx / Dd;
  int j = idx % Dd;
  float v = qf[b * Dd + j] + at[idx];
  size_t o = (size_t)row * DPn + 2 * Dd + j;
  us hb = f2bf(v);
  ch[o] = hb;
  cl[o] = f2bf(v - bf2f(hb));
}

// ---------------------------------------------------------------------------
// GRU combine for ALL candidate rows. gABall [1024 x 4608]: cols [0,2304) =
// x-gates (wih), cols [2304,4608) = h-gates (whh). Pre-split bf16 output.
// Row layout: [0,128): s=0 rows (b,a). [128,Mtot): 128+(((b*7+s-1)*16+a)*16+c).
// ---------------------------------------------------------------------------
__global__ void combine_all(const float* __restrict__ gABall,
                            const float* __restrict__ gh0,
                            const float* __restrict__ inps,
                            const float* __restrict__ state0,
                            us* __restrict__ Hh, us* __restrict__ Hl) {
  const int D4 = Dd / 4;
  const int LDG = 4608;
  int idx = blockIdx.x * 256 + threadIdx.x;
  if (idx >= Mtot * D4) return;
  int row = idx / D4, j = (idx - row * D4) * 4;
  const float* gp;
  const float* ghp;
  const float* stp;
  if (row < 128) {
    int b = row >> 4, a = row & 15;
    gp = gABall + ((size_t)(b * NST) * An + a) * LDG;
    ghp = gh0;
    stp = state0;
  } else {
    int r = row - 128;
    int c = r & 15; r >>= 4;
    int a = r & 15; r >>= 4;
    int sm1 = r % 7, b = r / 7;
    size_t prev = (size_t)(b * NST + sm1) * An + c;
    gp = gABall + ((size_t)(b * NST + sm1 + 1) * An + a) * LDG;
    ghp = gABall + prev * LDG + GSn;
    stp = inps + prev * Dd;
  }
  float4 ir4 = *(const float4*)(gp + j);
  float4 iz4 = *(const float4*)(gp + Dd + j);
  float4 in4 = *(const float4*)(gp + 2 * Dd + j);
  float4 hr4 = *(const float4*)(ghp + j);
  float4 hz4 = *(const float4*)(ghp + Dd + j);
  float4 hn4 = *(const float4*)(ghp + 2 * Dd + j);
  float4 st4 = *(const float4*)(stp + j);
  float ir[4] = {ir4.x, ir4.y, ir4.z, ir4.w};
  float iz[4] = {iz4.x, iz4.y, iz4.z, iz4.w};
  float in_[4] = {in4.x, in4.y, in4.z, in4.w};
  float hr[4] = {hr4.x, hr4.y, hr4.z, hr4.w};
  float hz[4] = {hz4.x, hz4.y, hz4.z, hz4.w};
  float hn[4] = {hn4.x, hn4.y, hn4.z, hn4.w};
  float st[4] = {st4.x, st4.y, st4.z, st4.w};
  union { us u[4]; uint2 w; } oh, ol;
#pragma unroll
  for (int t = 0; t < 4; t++) {
    float rg = 1.f / (1.f + expf(-(ir[t] + hr[t])));
    float zg = 1.f / (1.f + expf(-(iz[t] + hz[t])));
    float ng = tanhf(in_[t] + rg * hn[t]);
    float v = (1.f - zg) * ng + zg * st[t];
    us hb = f2bf(v);
    oh.u[t] = hb;
    ol.u[t] = f2bf(v - bf2f(hb));
  }
  *(uint2*)&Hh[(size_t)row * Dd + j] = oh.w;
  *(uint2*)&Hl[(size_t)row * Dd + j] = ol.w;
}

// ---------------------------------------------------------------------------
// pick: walk the argmax chain over logit partials (12 n-tiles).
// ---------------------------------------------------------------------------
__global__ __launch_bounds__(64) void pick_k(const float* __restrict__ Lpart,
                                             const float* __restrict__ b2v,
                                             float* __restrict__ out) {
  int b = blockIdx.x;
  int lane = threadIdx.x;
  int c = 0;
  float b2 = b2v[0];
  for (int s = 0; s < NST; s++) {
    int row;
    if (s == 0) row = b * 16 + (lane & 15);
    else row = 128 + (((b * 7 + (s - 1)) * 16 + (lane & 15)) * 16 + c);
    float v = 0.f;
#pragma unroll
    for (int t = 0; t < 12; t++) v += Lpart[(size_t)t * Mtot + row];
    v += b2;
    if (lane < 16) out[(size_t)(b * NST + s) * An + lane] = v;
    float bv = (lane < 16) ? v : -1e30f;
    int bi = (lane < 16) ? lane : 999;
#pragma unroll
    for (int off = 1; off < 16; off <<= 1) {
      float ov = __shfl_xor(bv, off);
      int oi = __shfl_xor(bi, off);
      if (ov > bv || (ov == bv && oi < bi)) { bv = ov; bi = oi; }
    }
    c = __shfl(bi, 0);
  }
}

// ---------------------------------------------------------------------------
static inline void mm2(const us* Ah, const us* Al, int lda, const us* Bh, const us* Bl,
                       const float* bias, const float* bias2, int nsplit,
                       float* Cf, int ldc, us* Ch, us* Cl, int ldch,
                       int M, int N, int K, int relu, hipStream_t st) {
  dim3 g(N / 64, M / 64);
  mfma_nt<<<g, 256, 0, st>>>(Ah, Al, lda, Bh, Bl, bias, bias2, nsplit,
                             Cf, ldc, Ch, Cl, ldch, K, relu);
}
static inline void mm(const us* Ah, const us* Al, int lda, const us* Bh, const us* Bl,
                      const float* bias, float* Cf, int ldc, us* Ch, us* Cl, int ldch,
                      int M, int N, int K, int relu, hipStream_t st) {
  mm2(Ah, Al, lda, Bh, Bl, bias, bias, 1 << 30, Cf, ldc, Ch, Cl, ldch, M, N, K, relu, st);
}
static inline void sgemm(const float* A, const float* W, const float* bias, float* C,
                         int M, int N, int K, int lda, int ldc, int relu, hipStream_t st) {
  dim3 g((N + 63) / 64, (M + 63) / 64);
  gemm_s<<<g, 256, 0, st>>>(A, W, bias, C, M, N, K, lda, ldc, relu);
}
static inline void split(const float* x, us* h, us* l, int n, hipStream_t st) {
  int n4 = n >> 2;
  int blocks = (n4 + 255) / 256;
  if (blocks > 2048) blocks = 2048;
  split_k<<<blocks, 256, 0, st>>>(x, h, l, n4);
}

extern "C" void kernel_launch(void* const* d_in, const int* in_sizes, int n_in,
                              void* d_out, int out_size, void* d_ws, size_t ws_size,
                              hipStream_t stream) {
  const float* video     = (const float*)d_in[0];
  const float* script    = (const float*)d_in[1];
  const float* question  = (const float*)d_in[2];
  const float* a_texts   = (const float*)d_in[3];
  const float* a_buttons = (const float*)d_in[4];
  const float* v_w1 = (const float*)d_in[5];
  const float* v_b1 = (const float*)d_in[6];
  const float* v_w2 = (const float*)d_in[7];
  const float* v_b2 = (const float*)d_in[8];
  const float* t_w1 = (const float*)d_in[9];
  const float* t_b1 = (const float*)d_in[10];
  const float* t_w2 = (const float*)d_in[11];
  const float* t_b2 = (const float*)d_in[12];
  const float* pre_w1 = (const float*)d_in[13];
  const float* pre_b1 = (const float*)d_in[14];
  const float* pre_w2 = (const float*)d_in[15];
  const float* pre_b2 = (const float*)d_in[16];
  const float* s2v_win  = (const float*)d_in[17];
  const float* s2v_bin  = (const float*)d_in[18];
  const float* s2v_wout = (const float*)d_in[19];
  const float* s2v_bout = (const float*)d_in[20];
  const float* qa_win  = (const float*)d_in[21];
  const float* qa_bin  = (const float*)d_in[22];
  const float* qa_wout = (const float*)d_in[23];
  const float* qa_bout = (const float*)d_in[24];
  const float* gru_wih = (const float*)d_in[25];
  const float* gru_whh = (const float*)d_in[26];
  const float* gru_bih = (const float*)d_in[27];
  const float* gru_bhh = (const float*)d_in[28];
  const float* proj_w1 = (const float*)d_in[29];
  const float* proj_b1 = (const float*)d_in[30];
  const float* proj_w2 = (const float*)d_in[31];
  const float* proj_b2 = (const float*)d_in[32];
  const float* state0  = (const float*)d_in[33];
  (void)in_sizes; (void)n_in; (void)out_size; (void)ws_size;

  constexpr int W589  = 768 * 768;
  constexpr int W1769 = 2304 * 768;
  constexpr int W9437 = 3072 * 3072;
  constexpr int W2359 = 768 * 3072;
  constexpr int SMe   = 1024 * 768;
  constexpr int BIGe  = 4096 * 768;

  char* base = (char*)d_ws;
  char* RW1 = base;                   // 9,437,184 : phase-A weights -> gABall(head)
  char* RW2 = RW1 + 9437184;          // 9,437,184 : s2v/qa/pre_w2 weights -> gABall(tail)
  char* R1  = RW2 + 9437184;          // 28,311,552
  char* R2  = R1 + 28311552;          // 12,582,912
  char* X   = R2 + 12582912;          // 25,165,824
  char* P   = X + 25165824;           // abin + Hh/Hl tail overlap
  char* P2  = P + 6815744;            // persistents

  // RW1
  us* vw1h = (us*)RW1;        us* vw1l = vw1h + W589;
  us* vw2h = vw1l + W589;     us* vw2l = vw2h + W589;
  us* tw1h = vw2l + W589;     us* tw1l = tw1h + W589;
  us* tw2h = tw1l + W589;     us* tw2l = tw2h + W589;
  // RW2
  us* s2vwh = (us*)RW2;       us* s2vwl = s2vwh + W1769;
  us* s2voh = s2vwl + W1769;  us* s2vol = s2voh + W589;
  us* qawh  = (us*)RW2;       us* qawl  = qawh + W1769;
  us* qaoh  = qawl + W1769;   us* qaol  = qaoh + W589;
  us* pw2h  = (us*)RW2;       us* pw2l  = pw2h + W2359;
  float* gABall = (float*)RW1;          // [1024 x 4608] f32, spans RW1+RW2
  // R1 timeline
  us* vidh = (us*)R1;         us* vidl = vidh + BIGe;
  us* hidh = vidl + BIGe;     us* hidl = hidh + BIGe;
  us* inTh = (us*)R1;         us* inTl = inTh + 2 * SMe;   // 2048x768 inputs
  us* hid2h = (us*)(R1 + 12582912); us* hid2l = hid2h + 2 * SMe;
  float* kvproj = (float*)R1;
  float* qproj  = kvproj + (size_t)4096 * 1536;
  float* kv2 = (float*)R1;
  float* qp2 = (float*)(R1 + 6291456);
  float* S2  = (float*)(R1 + 9437184);
  us* abhh = (us*)(R1 + 15728640); us* abhl = abhh + SMe;
  us* pw1h = (us*)R1;         us* pw1l = pw1h + W9437;     // spans into R2
  us* gwALLh = (us*)R1;                                    // [4608x768]
  us* gwALLl = (us*)(R1 + 7077888);
  us* pjw1h  = (us*)(R1 + 14155776); us* pjw1l = pjw1h + W589;
  // R2
  us* vh = (us*)R2;           us* vl = vh + BIGe;
  us* aoh = (us*)(R2 + 3145728); us* aol = aoh + SMe;
  us* Hh = (us*)R2;           us* Hl = Hh + (size_t)Mtot * Dd;  // spans R2+X+P
  // X
  float* S1 = (float*)X;
  us* cath = (us*)X;          us* catl = cath + (size_t)1024 * DPn;
  us* prehh = (us*)(X + 12582912); us* prehl = prehh + (size_t)1024 * DPn;
  // P (overwritten by Hl tail after abin dead)
  us* abinh = (us*)P;         us* abinl = abinh + SMe;
  // P2 persistents
  us* sc2h   = (us*)P2;                       // 2048x768 split (script|a_texts)
  us* sc2l   = sc2h + 2 * SMe;
  float* scat_f = (float*)(P2 + 6291456);     // 2048x768 f32
  float* vatt   = (float*)(P2 + 12582912);
  float* inps_f = (float*)(P2 + 15728640);
  us* inpsh = (us*)(P2 + 18874368); us* inpsl = inpsh + SMe;
  float* qf    = (float*)(P2 + 22020096);
  float* qhid  = (float*)(P2 + 22044672);
  float* gh0   = (float*)(P2 + 22069248);
  float* Lpart = (float*)(P2 + 22085632);     // 12 x 14464 f32
  float* at_f  = scat_f + (size_t)1024 * Dd;  // rows 1024..2047
  us* sch = sc2h;  us* scl = sc2l;            // rows 0..1023

  // ---- phase A: weight splits + video MLP ----
  split4_k<<<dim3(1024, 4), 256, 0, stream>>>(v_w1, vw1h, vw1l, W589,
                                              v_w2, vw2h, vw2l, W589,
                                              t_w1, tw1h, tw1l, W589,
                                              t_w2, tw2h, tw2l, W589);
  split(video, vidh, vidl, BIGe, stream);
  mm(vidh, vidl, Dd, vw1h, vw1l, v_b1, nullptr, 0, hidh, hidl, Dd, 4096, Dd, Dd, 1, stream);
  mm(hidh, hidl, Dd, vw2h, vw2l, v_b2, nullptr, 0, vh, vl, Dd, 4096, Dd, Dd, 0, stream);
  // script + a_texts merged t-MLP (2048 rows) + a_buttons input split
  split4_k<<<dim3(1024, 3), 256, 0, stream>>>(script, inTh, inTl, SMe,
                                              a_texts, inTh + SMe, inTl + SMe, SMe,
                                              a_buttons, abinh, abinl, SMe,
                                              nullptr, nullptr, nullptr, 0);
  mm(inTh, inTl, Dd, tw1h, tw1l, t_b1, nullptr, 0, hid2h, hid2l, Dd, 2048, Dd, Dd, 1, stream);
  mm(hid2h, hid2l, Dd, tw2h, tw2l, t_b2, scat_f, Dd, sc2h, sc2l, Dd, 2048, Dd, Dd, 0, stream);
  sgemm(question, t_w1, t_b1, qhid, Bn, Dd, Dd, Dd, Dd, 1, stream);
  sgemm(qhid, t_w2, t_b2, qf, Bn, Dd, Dd, Dd, Dd, 0, stream);

  // ---- s2v attention (K/V merged: N=1536) ----
  split4_k<<<dim3(1024, 2), 256, 0, stream>>>(s2v_win, s2vwh, s2vwl, W1769,
                                              s2v_wout, s2voh, s2vol, W589,
                                              nullptr, nullptr, nullptr, 0,
                                              nullptr, nullptr, nullptr, 0);
  mm(vh, vl, Dd, s2vwh + (size_t)Dd * Dd, s2vwl + (size_t)Dd * Dd, s2v_bin + Dd,
     kvproj, 1536, nullptr, nullptr, 0, 4096, 1536, Dd, 0, stream);
  mm(sch, scl, Dd, s2vwh, s2vwl, s2v_bin, qproj, Dd, nullptr, nullptr, 0, 1024, Dd, Dd, 0, stream);
  att_qk<<<dim3(Bn * NH, TSn / 32, TVn / 64), 256, 0, stream>>>(qproj, kvproj, S1,
                                                                TSn, TVn, 1, 1536, 0.125f);
  softmax_rows<<<Bn * NH * TSn, 256, 0, stream>>>(S1, TVn);
  att_pv<<<dim3(Bn * NH, TSn / 32), 256, 0, stream>>>(S1, kvproj + Dd, aoh, aol,
                                                      TSn, TVn, 1, 1536);
  mm(aoh, aol, Dd, s2voh, s2vol, s2v_bout, vatt, Dd, nullptr, nullptr, 0, 1024, Dd, Dd, 0, stream);

  // ---- phase B: ab MLP, qa attention ----
  mm(abinh, abinl, Dd, vw1h, vw1l, v_b1, nullptr, 0, abhh, abhl, Dd, 1024, Dd, Dd, 1, stream);
  mm(abhh, abhl, Dd, vw2h, vw2l, v_b2, nullptr, 0, cath + 3 * Dd, catl + 3 * Dd, DPn,
     1024, Dd, Dd, 0, stream);
  qa_add<<<(1024 * Dd + 255) / 256, 256, 0, stream>>>(qf, at_f, cath, catl);
  split4_k<<<dim3(1024, 2), 256, 0, stream>>>(qa_win, qawh, qawl, W1769,
                                              qa_wout, qaoh, qaol, W589,
                                              nullptr, nullptr, nullptr, 0,
                                              nullptr, nullptr, nullptr, 0);
  mm(sch, scl, Dd, qawh + (size_t)Dd * Dd, qawl + (size_t)Dd * Dd, qa_bin + Dd,
     kv2, 1536, nullptr, nullptr, 0, 1024, 1536, Dd, 0, stream);
  mm(cath + 2 * Dd, catl + 2 * Dd, DPn, qawh, qawl, qa_bin, qp2, Dd, nullptr, nullptr, 0,
     1024, Dd, Dd, 0, stream);
  att_qk<<<dim3(Bn * NST * NH, 1, TSn / 64), 256, 0, stream>>>(qp2, kv2, S2,
                                                               An, TSn, NST, 1536, 0.125f);
  softmax_rows<<<Bn * NST * NH * An, 256, 0, stream>>>(S2, TSn);
  att_pv<<<dim3(Bn * NST * NH, 1), 256, 0, stream>>>(S2, kv2 + Dd, aoh, aol,
                                                     An, TSn, NST, 1536);
  mm(aoh, aol, Dd, qaoh, qaol, qa_bout, nullptr, 0, cath + Dd, catl + Dd, DPn,
     1024, Dd, Dd, 0, stream);
  qv2_k<<<1024, 256, 0, stream>>>(S2, vatt, cath, catl);

  // ---- pre-MLP + merged GRU gates ----
  split(pre_w1, pw1h, pw1l, W9437, stream);
  mm(cath, catl, DPn, pw1h, pw1l, pre_b1, nullptr, 0, prehh, prehl, DPn,
     1024, DPn, DPn, 1, stream);
  split4_k<<<dim3(1024, 4), 256, 0, stream>>>(pre_w2, pw2h, pw2l, W2359,
                                              gru_wih, gwALLh, gwALLl, W1769,
                                              gru_whh, gwALLh + W1769, gwALLl + W1769, W1769,
                                              proj_w1, pjw1h, pjw1l, W589);
  mm(prehh, prehl, DPn, pw2h, pw2l, pre_b2, inps_f, Dd, inpsh, inpsl, Dd,
     1024, Dd, DPn, 0, stream);
  mm2(inpsh, inpsl, Dd, gwALLh, gwALLl, gru_bih, gru_bhh, GSn,
      gABall, 4608, nullptr, nullptr, 0, 1024, 4608, Dd, 0, stream);
  sgemm(state0, gru_whh, gru_bhh, gh0, 1, GSn, Dd, Dd, GSn, 0, stream);

  // ---- candidate enumeration + logits + argmax chain ----
  combine_all<<<(Mtot * (Dd / 4) + 255) / 256, 256, 0, stream>>>(gABall, gh0, inps_f,
                                                                 state0, Hh, Hl);
  mfma_logit<<<dim3(Dd / 64, Mtot / 64), 256, 0, stream>>>(Hh, Hl, pjw1h, pjw1l,
                                                           proj_b1, proj_w2, Lpart);
  pick_k<<<Bn, 64, 0, stream>>>(Lpart, proj_b2, (float*)d_out);
}